// Round 2
// baseline (1899.357 us; speedup 1.0000x reference)
//
#include <hip/hip_runtime.h>
#include <hip/hip_bf16.h>
#include <math.h>

__device__ __forceinline__ float lk(float v){ return v >= 0.f ? v : 0.01f*v; }

// ---------------------------------------------------------------------------
// Hypernet conv1 (per 32-batch chunk): x[32,16,12288] f32, w[32,16,7],
// reflect-same, leaky, meanpool4 -> h1[32,32,3072] f32.
// Thread = (b, oq of 8, pg of 768): 4 output channels x 16 conv t (4 pooled).
// ---------------------------------------------------------------------------
__global__ __launch_bounds__(256) void k_hconv1(const float* __restrict__ x,
        const float* __restrict__ w, const float* __restrict__ bias,
        float* __restrict__ out)
{
    int g = blockIdx.x*256 + threadIdx.x;
    int pg = g % 768; int rest = g / 768; int oq = rest & 7; int b = rest >> 3;
    int t0 = pg*16 - 3;
    int tt[22];
    #pragma unroll
    for (int j=0;j<22;j++){ int t=t0+j; tt[j] = t<0 ? -t : (t>=12288 ? 2*12288-2-t : t); }
    float acc[4][16];
    #pragma unroll
    for (int u=0;u<4;u++)
        #pragma unroll
        for (int i=0;i<16;i++) acc[u][i]=0.f;
    for (int ic=0; ic<16; ic++){
        const float* xc = x + ((size_t)(b*16+ic))*12288;
        float xr[22];
        #pragma unroll
        for (int j=0;j<22;j++) xr[j] = xc[tt[j]];
        float wr[4][7];
        #pragma unroll
        for (int u=0;u<4;u++)
            #pragma unroll
            for (int s=0;s<7;s++) wr[u][s] = w[(((oq*4+u)*16)+ic)*7+s];
        #pragma unroll
        for (int u=0;u<4;u++)
            #pragma unroll
            for (int s=0;s<7;s++)
                #pragma unroll
                for (int l=0;l<16;l++) acc[u][l] += wr[u][s]*xr[l+s];
    }
    #pragma unroll
    for (int u=0;u<4;u++){
        int o = oq*4+u;
        float bv = bias[o];
        float* op = out + ((size_t)(b*32+o))*3072 + pg*4;
        #pragma unroll
        for (int q=0;q<4;q++){
            float m = 0.f;
            #pragma unroll
            for (int j=0;j<4;j++) m += lk(acc[u][4*q+j]+bv);
            op[q] = m*0.25f;
        }
    }
}

// ---------------------------------------------------------------------------
// Hypernet conv2 (per 32-batch chunk): h1[32,32,3072] f32, w[64,32,7],
// reflect-same, leaky, meanpool4 -> h2chunk[32,64,768] f32.
// Thread = (b, oq of 16, pg of 192).
// ---------------------------------------------------------------------------
__global__ __launch_bounds__(256) void k_hconv2(const float* __restrict__ in,
        const float* __restrict__ w, const float* __restrict__ bias,
        float* __restrict__ out)
{
    int g = blockIdx.x*256 + threadIdx.x;
    int pg = g % 192; int rest = g / 192; int oq = rest & 15; int b = rest >> 4;
    int t0 = pg*16 - 3;
    int tt[22];
    #pragma unroll
    for (int j=0;j<22;j++){ int t=t0+j; tt[j] = t<0 ? -t : (t>=3072 ? 2*3072-2-t : t); }
    float acc[4][16];
    #pragma unroll
    for (int u=0;u<4;u++)
        #pragma unroll
        for (int i=0;i<16;i++) acc[u][i]=0.f;
    for (int ic=0; ic<32; ic++){
        const float* xc = in + ((size_t)(b*32+ic))*3072;
        float xr[22];
        #pragma unroll
        for (int j=0;j<22;j++) xr[j] = xc[tt[j]];
        float wr[4][7];
        #pragma unroll
        for (int u=0;u<4;u++)
            #pragma unroll
            for (int s=0;s<7;s++) wr[u][s] = w[(((oq*4+u)*32)+ic)*7+s];
        #pragma unroll
        for (int u=0;u<4;u++)
            #pragma unroll
            for (int s=0;s<7;s++)
                #pragma unroll
                for (int l=0;l<16;l++) acc[u][l] += wr[u][s]*xr[l+s];
    }
    #pragma unroll
    for (int u=0;u<4;u++){
        int o = oq*4+u;
        float bv = bias[o];
        float* op = out + ((size_t)(b*64+o))*768 + pg*4;
        #pragma unroll
        for (int q=0;q<4;q++){
            float m = 0.f;
            #pragma unroll
            for (int j=0;j<4;j++) m += lk(acc[u][4*q+j]+bv);
            op[q] = m*0.25f;
        }
    }
}

// ---------------------------------------------------------------------------
// Hypernet conv3 + tanh: h2[128,64,768] f32, w[8,64,7] -> latent[128,6144]
// ---------------------------------------------------------------------------
__global__ __launch_bounds__(256) void k_hconv3(const float* __restrict__ in,
        const float* __restrict__ w, const float* __restrict__ bias,
        float* __restrict__ latent)
{
    int g = blockIdx.x*256 + threadIdx.x;
    int ug = g % 96; int rest = g / 96; int c = rest & 7; int b = rest >> 3;
    int t0 = ug*8 - 3;
    int tt[14];
    #pragma unroll
    for (int j=0;j<14;j++){ int t=t0+j; tt[j] = t<0 ? -t : (t>=768 ? 2*768-2-t : t); }
    float acc[8];
    #pragma unroll
    for (int i=0;i<8;i++) acc[i]=0.f;
    for (int ic=0; ic<64; ic++){
        const float* xc = in + ((size_t)(b*64+ic))*768;
        float xr[14];
        #pragma unroll
        for (int j=0;j<14;j++) xr[j] = xc[tt[j]];
        const float* wp = w + (c*64+ic)*7;
        float wr[7];
        #pragma unroll
        for (int s=0;s<7;s++) wr[s] = wp[s];
        #pragma unroll
        for (int s=0;s<7;s++)
            #pragma unroll
            for (int l=0;l<8;l++) acc[l] += wr[s]*xr[l+s];
    }
    float bv = bias[c];
    float* op = latent + (size_t)b*6144 + c*768 + ug*8;
    #pragma unroll
    for (int l=0;l<8;l++) op[l] = tanhf(acc[l]+bv);
}

// ---------------------------------------------------------------------------
// t1 = leaky(latent @ hl1^T): one wave per (b,n); dot over 6144.
// ---------------------------------------------------------------------------
__global__ __launch_bounds__(64) void k_lin1(const float* __restrict__ latent,
        const float* __restrict__ hl1, float* __restrict__ t1)
{
    int b = blockIdx.x / 96, n = blockIdx.x % 96;
    int lane = threadIdx.x;
    const float* lp = latent + (size_t)b*6144;
    const float* wp = hl1 + (size_t)n*6144;
    float s = 0.f;
    for (int i=lane; i<6144; i+=64) s += lp[i]*wp[i];
    #pragma unroll
    for (int off=32; off; off>>=1) s += __shfl_down(s, off);
    if (lane==0) t1[b*96+n] = lk(s);
}

// ---------------------------------------------------------------------------
// logits = t1 @ hl2^T; top-5 (descending, ties -> lower index); n0 = #(idx<6)
// ---------------------------------------------------------------------------
__global__ __launch_bounds__(128) void k_topk(const float* __restrict__ t1,
        const float* __restrict__ hl2, int* __restrict__ idxb, float* __restrict__ n0f)
{
    __shared__ float lg[96];
    int b = blockIdx.x, n = threadIdx.x;
    if (n < 96){
        float s = 0.f;
        const float* tp = t1 + b*96;
        const float* wp = hl2 + n*96;
        for (int m=0;m<96;m++) s += tp[m]*wp[m];
        lg[n] = s;
    }
    __syncthreads();
    if (threadIdx.x == 0){
        unsigned long long u0=0ull, u1=0ull;
        float n0 = 0.f;
        for (int k=0;k<5;k++){
            float best = -3.4e38f; int bi = 0;
            for (int m=0;m<96;m++){
                bool used = m<64 ? ((u0>>m)&1ull) : ((u1>>(m-64))&1ull);
                if (!used && lg[m] > best){ best = lg[m]; bi = m; }
            }
            if (bi<64) u0 |= 1ull<<bi; else u1 |= 1ull<<(bi-64);
            idxb[b*5+k] = bi;
            if (bi < 6) n0 += 1.f;
        }
        n0f[b] = n0;
    }
}

// ---------------------------------------------------------------------------
// Grouped idx conv ks=15 + bias(n0*gb0) + leaky + maxpool4
// -> zp[128,64,508] f32.  Block = (b, qc of 4), 256 thr.
// ---------------------------------------------------------------------------
__global__ __launch_bounds__(256) void k_gconv(const float* __restrict__ x,
        const int* __restrict__ idxb, const float* __restrict__ n0f,
        const float* __restrict__ gw, const float* __restrict__ gb0,
        float* __restrict__ zp)
{
    __shared__ float xs[5][522];
    int b = blockIdx.x >> 2, qc = blockIdx.x & 3;
    int tid = threadIdx.x;
    int l0 = qc*508;
    for (int j=tid; j<5*522; j+=256){
        int k = j/522, u = j - k*522;
        int n = idxb[b*5+k];
        xs[k][u] = x[(size_t)b*196608 + n*2048 + l0 + u];
    }
    __syncthreads();
    int o = tid >> 2, qs = tid & 3;
    float wreg[5][15];
    #pragma unroll
    for (int k=0;k<5;k++){
        int n = idxb[b*5+k]; int gi = n/6;
        const float* wp = gw + gi*960 + o*15;
        #pragma unroll
        for (int s=0;s<15;s++) wreg[k][s] = wp[s];
    }
    float bv = n0f[b]*gb0[o];
    for (int q=qs; q<127; q+=4){
        float mx = -3.4e38f;
        #pragma unroll
        for (int j=0;j<4;j++){
            int lb = 4*q + j;
            float s = bv;
            #pragma unroll
            for (int k=0;k<5;k++)
                #pragma unroll
                for (int sp=0;sp<15;sp++) s += wreg[k][sp]*xs[k][lb+sp];
            mx = fmaxf(mx, lk(s));
        }
        zp[((size_t)(b*64+o))*508 + qc*127 + q] = mx;
    }
}

// ---------------------------------------------------------------------------
// Encoder conv2 ks=7 valid + leaky + maxpool4: zp[128,64,508] ->
// p2[128,128,125].  Thread = (b, oq of 32, qg of 25): 4 out-ch x 5 pooled.
// ---------------------------------------------------------------------------
__global__ __launch_bounds__(256) void k_econv2(const float* __restrict__ in,
        const float* __restrict__ w, const float* __restrict__ bias,
        float* __restrict__ p2)
{
    int g = blockIdx.x*256 + threadIdx.x;
    int qg = g % 25; int rest = g / 25; int oq = rest & 31; int b = rest >> 5;
    int l0 = qg*20;
    float acc[4][20];
    #pragma unroll
    for (int u=0;u<4;u++)
        #pragma unroll
        for (int i=0;i<20;i++) acc[u][i]=0.f;
    for (int ic=0; ic<64; ic++){
        const float* xc = in + ((size_t)(b*64+ic))*508 + l0;
        float xr[26];
        #pragma unroll
        for (int j=0;j<26;j++) xr[j] = xc[j];
        float wr[4][7];
        #pragma unroll
        for (int u=0;u<4;u++)
            #pragma unroll
            for (int s=0;s<7;s++) wr[u][s] = w[(((oq*4+u)*64)+ic)*7+s];
        #pragma unroll
        for (int u=0;u<4;u++)
            #pragma unroll
            for (int s=0;s<7;s++)
                #pragma unroll
                for (int l=0;l<20;l++) acc[u][l] += wr[u][s]*xr[l+s];
    }
    #pragma unroll
    for (int u=0;u<4;u++){
        int o = oq*4+u;
        float bv = bias[o];
        float* op = p2 + ((size_t)(b*128+o))*125 + qg*5;
        #pragma unroll
        for (int q=0;q<5;q++){
            float mx = -3.4e38f;
            #pragma unroll
            for (int j=0;j<4;j++) mx = fmaxf(mx, lk(acc[u][4*q+j]+bv));
            op[q] = mx;
        }
    }
}

// ---------------------------------------------------------------------------
// Sliding column sums: ssum[b,ic,s] = sum_{l=0..118} p2[b,ic,l+s], s=0..6
// ---------------------------------------------------------------------------
__global__ __launch_bounds__(256) void k_colsum(const float* __restrict__ p2,
        float* __restrict__ ssum)
{
    int g = blockIdx.x*256 + threadIdx.x;   // 16384 threads = (b,ic)
    int ic = g & 127, b = g >> 7;
    const float* pp = p2 + ((size_t)(b*128+ic))*125;
    float c = 0.f;
    for (int t=0;t<119;t++) c += pp[t];
    float* op = ssum + (size_t)(b*128+ic)*7;
    op[0] = c;
    #pragma unroll
    for (int s=0;s<6;s++){ c = c - pp[s] + pp[s+119]; op[s+1] = c; }
}

// ---------------------------------------------------------------------------
// feat[b,o] = eb3[o] + (1/119) * sum_{ic,s} ew3[o,ic,s]*ssum[b,ic,s]
// ---------------------------------------------------------------------------
__global__ __launch_bounds__(128) void k_feat(const float* __restrict__ ssum,
        const float* __restrict__ w, const float* __restrict__ bias,
        float* __restrict__ feat)
{
    __shared__ float ss[896];
    int b = blockIdx.x, o = threadIdx.x;
    for (int j=threadIdx.x; j<896; j+=128) ss[j] = ssum[(size_t)b*896 + j];
    __syncthreads();
    const float* wp = w + o*896;
    float s = 0.f;
    for (int j=0;j<896;j++) s += wp[j]*ss[j];
    feat[b*128+o] = s*(1.f/119.f) + bias[o];
}

// ---------------------------------------------------------------------------
// classifier + log_softmax -> out f32 [128,5]
// ---------------------------------------------------------------------------
__global__ __launch_bounds__(64) void k_cls(const float* __restrict__ feat,
        const float* __restrict__ cw, const float* __restrict__ cb,
        float* __restrict__ out)
{
    __shared__ float lg[5];
    int b = blockIdx.x;
    if (threadIdx.x < 5){
        const float* fp = feat + b*128;
        const float* wp = cw + threadIdx.x*128;
        float s = 0.f;
        for (int o=0;o<128;o++) s += fp[o]*wp[o];
        lg[threadIdx.x] = s + cb[threadIdx.x];
    }
    __syncthreads();
    if (threadIdx.x == 0){
        float mx = -3.4e38f;
        for (int c=0;c<5;c++) mx = fmaxf(mx, lg[c]);
        float se = 0.f;
        for (int c=0;c<5;c++) se += expf(lg[c]-mx);
        float lse = mx + logf(se);
        for (int c=0;c<5;c++) out[b*5+c] = lg[c]-lse;
    }
}

extern "C" void kernel_launch(void* const* d_in, const int* in_sizes, int n_in,
                              void* d_out, int out_size, void* d_ws, size_t ws_size,
                              hipStream_t stream)
{
    const float* x   = (const float*)d_in[0];
    // d_in[1] = epoch (int, unused in eval forward)
    const float* hw1 = (const float*)d_in[2];
    const float* hb1 = (const float*)d_in[3];
    const float* hw2 = (const float*)d_in[4];
    const float* hb2 = (const float*)d_in[5];
    const float* hw3 = (const float*)d_in[6];
    const float* hb3 = (const float*)d_in[7];
    const float* hl1 = (const float*)d_in[8];
    const float* hl2 = (const float*)d_in[9];
    const float* gw  = (const float*)d_in[10];
    const float* gb0 = (const float*)d_in[11];
    const float* ew2 = (const float*)d_in[12];
    const float* eb2 = (const float*)d_in[13];
    const float* ew3 = (const float*)d_in[14];
    const float* eb3 = (const float*)d_in[15];
    const float* cw  = (const float*)d_in[16];
    const float* cb  = (const float*)d_in[17];
    float* out = (float*)d_out;

    // workspace (floats), peak 40.9 MB:
    //   h2      @ 0          : 128*64*768   = 6,291,456 f
    //   h1buf   @ 6,291,456  : 32*32*3072   = 3,145,728 f   (per-chunk, reused)
    //   latent  @ 9,437,184  : 128*6144     =   786,432 f   (ends 10,223,616)
    //   then reuse [0 ..) after h2 is dead (post-hconv3):
    //   t1 @ 0, idxb @ 20k, n0f @ 22k, zp @ 30k, p2 @ 4.2M, ssum @ 6.3M, feat @ 6.5M
    float* f      = (float*)d_ws;
    float* h2     = f;
    float* h1buf  = f + 6291456;
    float* latent = f + 9437184;
    float* t1     = f;
    int*   idxb   = (int*)(f + 20000);
    float* n0f    = f + 22000;
    float* zp     = f + 30000;          // 4,161,536 f -> ends 4,191,536
    float* p2     = f + 4200000;        // 2,048,000 f -> ends 6,248,000
    float* ssum   = f + 6300000;        //   114,688 f
    float* feat   = f + 6500000;        //    16,384 f

    for (int c = 0; c < 4; c++){
        const float* xc = x + (size_t)c*32*16*12288;
        float* h2c = h2 + (size_t)c*32*64*768;
        k_hconv1<<<768, 256, 0, stream>>>(xc, hw1, hb1, h1buf);
        k_hconv2<<<384, 256, 0, stream>>>(h1buf, hw2, hb2, h2c);
    }
    k_hconv3<<<384, 256, 0, stream>>>(h2, hw3, hb3, latent);
    k_lin1<<<12288, 64, 0, stream>>>(latent, hl1, t1);
    k_topk<<<128, 128, 0, stream>>>(t1, hl2, idxb, n0f);
    k_gconv<<<512, 256, 0, stream>>>(x, idxb, n0f, gw, gb0, zp);
    k_econv2<<<400, 256, 0, stream>>>(zp, ew2, eb2, p2);
    k_colsum<<<64, 256, 0, stream>>>(p2, ssum);
    k_feat<<<128, 128, 0, stream>>>(ssum, ew3, eb3, feat);
    k_cls<<<128, 64, 0, stream>>>(feat, cw, cb, out);
}

// Round 3
// 1626.969 us; speedup vs baseline: 1.1674x; 1.1674x over previous
//
#include <hip/hip_runtime.h>
#include <hip/hip_bf16.h>
#include <math.h>

__device__ __forceinline__ float lk(float v){ return v >= 0.f ? v : 0.01f*v; }

// ---------------------------------------------------------------------------
// Hypernet conv1: x[bs,16,12288] f32, w[32,16,7], reflect-same, leaky,
// meanpool4 -> h1[bs,32,3072] f32.  Thread = (b, oq of 8, pg of 768).
// ---------------------------------------------------------------------------
__global__ __launch_bounds__(256) void k_hconv1(const float* __restrict__ x,
        const float* __restrict__ w, const float* __restrict__ bias,
        float* __restrict__ out)
{
    int g = blockIdx.x*256 + threadIdx.x;
    int pg = g % 768; int rest = g / 768; int oq = rest & 7; int b = rest >> 3;
    int t0 = pg*16 - 3;
    int tt[22];
    #pragma unroll
    for (int j=0;j<22;j++){ int t=t0+j; tt[j] = t<0 ? -t : (t>=12288 ? 2*12288-2-t : t); }
    float acc[4][16];
    #pragma unroll
    for (int u=0;u<4;u++)
        #pragma unroll
        for (int i=0;i<16;i++) acc[u][i]=0.f;
    for (int ic=0; ic<16; ic++){
        const float* xc = x + ((size_t)(b*16+ic))*12288;
        float xr[22];
        #pragma unroll
        for (int j=0;j<22;j++) xr[j] = xc[tt[j]];
        float wr[4][7];
        #pragma unroll
        for (int u=0;u<4;u++)
            #pragma unroll
            for (int s=0;s<7;s++) wr[u][s] = w[(((oq*4+u)*16)+ic)*7+s];
        #pragma unroll
        for (int u=0;u<4;u++)
            #pragma unroll
            for (int s=0;s<7;s++)
                #pragma unroll
                for (int l=0;l<16;l++) acc[u][l] += wr[u][s]*xr[l+s];
    }
    #pragma unroll
    for (int u=0;u<4;u++){
        int o = oq*4+u;
        float bv = bias[o];
        float* op = out + ((size_t)(b*32+o))*3072 + pg*4;
        #pragma unroll
        for (int q=0;q<4;q++){
            float m = 0.f;
            #pragma unroll
            for (int j=0;j<4;j++) m += lk(acc[u][4*q+j]+bv);
            op[q] = m*0.25f;
        }
    }
}

// ---------------------------------------------------------------------------
// Hypernet conv2: h1[bs,32,3072] f32, w[64,32,7], reflect-same, leaky,
// meanpool4 -> h2[bs,64,768] f32.  Thread = (b, oq of 16, pg of 192).
// ---------------------------------------------------------------------------
__global__ __launch_bounds__(256) void k_hconv2(const float* __restrict__ in,
        const float* __restrict__ w, const float* __restrict__ bias,
        float* __restrict__ out)
{
    int g = blockIdx.x*256 + threadIdx.x;
    int pg = g % 192; int rest = g / 192; int oq = rest & 15; int b = rest >> 4;
    int t0 = pg*16 - 3;
    int tt[22];
    #pragma unroll
    for (int j=0;j<22;j++){ int t=t0+j; tt[j] = t<0 ? -t : (t>=3072 ? 2*3072-2-t : t); }
    float acc[4][16];
    #pragma unroll
    for (int u=0;u<4;u++)
        #pragma unroll
        for (int i=0;i<16;i++) acc[u][i]=0.f;
    for (int ic=0; ic<32; ic++){
        const float* xc = in + ((size_t)(b*32+ic))*3072;
        float xr[22];
        #pragma unroll
        for (int j=0;j<22;j++) xr[j] = xc[tt[j]];
        float wr[4][7];
        #pragma unroll
        for (int u=0;u<4;u++)
            #pragma unroll
            for (int s=0;s<7;s++) wr[u][s] = w[(((oq*4+u)*32)+ic)*7+s];
        #pragma unroll
        for (int u=0;u<4;u++)
            #pragma unroll
            for (int s=0;s<7;s++)
                #pragma unroll
                for (int l=0;l<16;l++) acc[u][l] += wr[u][s]*xr[l+s];
    }
    #pragma unroll
    for (int u=0;u<4;u++){
        int o = oq*4+u;
        float bv = bias[o];
        float* op = out + ((size_t)(b*64+o))*768 + pg*4;
        #pragma unroll
        for (int q=0;q<4;q++){
            float m = 0.f;
            #pragma unroll
            for (int j=0;j<4;j++) m += lk(acc[u][4*q+j]+bv);
            op[q] = m*0.25f;
        }
    }
}

// ---------------------------------------------------------------------------
// Hypernet conv3 stage A: ic-split partial sums.
// partial[icq][b][c][768], icq over 4 groups of 16 input channels.
// Thread = (icq, b, c, ug of 96): run of 8 positions.  Grid 1536 blocks.
// ---------------------------------------------------------------------------
__global__ __launch_bounds__(256) void k_hconv3a(const float* __restrict__ in,
        const float* __restrict__ w, float* __restrict__ partial)
{
    int g = blockIdx.x*256 + threadIdx.x;
    int ug = g % 96; int r = g / 96;
    int c = r & 7; int b = (r >> 3) & 127; int icq = r >> 10;
    int t0 = ug*8 - 3;
    int tt[14];
    #pragma unroll
    for (int j=0;j<14;j++){ int t=t0+j; tt[j] = t<0 ? -t : (t>=768 ? 2*768-2-t : t); }
    float acc[8];
    #pragma unroll
    for (int i=0;i<8;i++) acc[i]=0.f;
    for (int ic=icq*16; ic<icq*16+16; ic++){
        const float* xc = in + ((size_t)(b*64+ic))*768;
        float xr[14];
        #pragma unroll
        for (int j=0;j<14;j++) xr[j] = xc[tt[j]];
        const float* wp = w + (c*64+ic)*7;
        float wr[7];
        #pragma unroll
        for (int s=0;s<7;s++) wr[s] = wp[s];
        #pragma unroll
        for (int s=0;s<7;s++)
            #pragma unroll
            for (int l=0;l<8;l++) acc[l] += wr[s]*xr[l+s];
    }
    float* op = partial + ((size_t)(icq*1024 + b*8 + c))*768 + ug*8;
    #pragma unroll
    for (int l=0;l<8;l++) op[l] = acc[l];
}

// ---------------------------------------------------------------------------
// Hypernet conv3 stage B: combine 4 partials + bias + tanh -> latent[128,6144]
// ---------------------------------------------------------------------------
__global__ __launch_bounds__(256) void k_hconv3b(const float* __restrict__ partial,
        const float* __restrict__ bias, float* __restrict__ latent)
{
    int idx = blockIdx.x*256 + threadIdx.x;   // 786432 total
    int pos = idx % 768; int r = idx / 768;
    int c = r & 7; int b = r >> 3;
    float s = bias[c];
    #pragma unroll
    for (int q=0;q<4;q++) s += partial[((size_t)(q*1024 + b*8 + c))*768 + pos];
    latent[(size_t)b*6144 + c*768 + pos] = tanhf(s);
}

// ---------------------------------------------------------------------------
// Legacy single-stage conv3 (fallback path only)
// ---------------------------------------------------------------------------
__global__ __launch_bounds__(256) void k_hconv3(const float* __restrict__ in,
        const float* __restrict__ w, const float* __restrict__ bias,
        float* __restrict__ latent)
{
    int g = blockIdx.x*256 + threadIdx.x;
    int ug = g % 96; int rest = g / 96; int c = rest & 7; int b = rest >> 3;
    int t0 = ug*8 - 3;
    int tt[14];
    #pragma unroll
    for (int j=0;j<14;j++){ int t=t0+j; tt[j] = t<0 ? -t : (t>=768 ? 2*768-2-t : t); }
    float acc[8];
    #pragma unroll
    for (int i=0;i<8;i++) acc[i]=0.f;
    for (int ic=0; ic<64; ic++){
        const float* xc = in + ((size_t)(b*64+ic))*768;
        float xr[14];
        #pragma unroll
        for (int j=0;j<14;j++) xr[j] = xc[tt[j]];
        const float* wp = w + (c*64+ic)*7;
        float wr[7];
        #pragma unroll
        for (int s=0;s<7;s++) wr[s] = wp[s];
        #pragma unroll
        for (int s=0;s<7;s++)
            #pragma unroll
            for (int l=0;l<8;l++) acc[l] += wr[s]*xr[l+s];
    }
    float bv = bias[c];
    float* op = latent + (size_t)b*6144 + c*768 + ug*8;
    #pragma unroll
    for (int l=0;l<8;l++) op[l] = tanhf(acc[l]+bv);
}

// ---------------------------------------------------------------------------
// t1 = leaky(latent @ hl1^T): one wave per (b,n); dot over 6144.
// ---------------------------------------------------------------------------
__global__ __launch_bounds__(64) void k_lin1(const float* __restrict__ latent,
        const float* __restrict__ hl1, float* __restrict__ t1)
{
    int b = blockIdx.x / 96, n = blockIdx.x % 96;
    int lane = threadIdx.x;
    const float* lp = latent + (size_t)b*6144;
    const float* wp = hl1 + (size_t)n*6144;
    float s = 0.f;
    for (int i=lane; i<6144; i+=64) s += lp[i]*wp[i];
    #pragma unroll
    for (int off=32; off; off>>=1) s += __shfl_down(s, off);
    if (lane==0) t1[b*96+n] = lk(s);
}

// ---------------------------------------------------------------------------
// logits = t1 @ hl2^T; top-5 (descending, ties -> lower index); n0 = #(idx<6)
// ---------------------------------------------------------------------------
__global__ __launch_bounds__(128) void k_topk(const float* __restrict__ t1,
        const float* __restrict__ hl2, int* __restrict__ idxb, float* __restrict__ n0f)
{
    __shared__ float lg[96];
    int b = blockIdx.x, n = threadIdx.x;
    if (n < 96){
        float s = 0.f;
        const float* tp = t1 + b*96;
        const float* wp = hl2 + n*96;
        for (int m=0;m<96;m++) s += tp[m]*wp[m];
        lg[n] = s;
    }
    __syncthreads();
    if (threadIdx.x == 0){
        unsigned long long u0=0ull, u1=0ull;
        float n0 = 0.f;
        for (int k=0;k<5;k++){
            float best = -3.4e38f; int bi = 0;
            for (int m=0;m<96;m++){
                bool used = m<64 ? ((u0>>m)&1ull) : ((u1>>(m-64))&1ull);
                if (!used && lg[m] > best){ best = lg[m]; bi = m; }
            }
            if (bi<64) u0 |= 1ull<<bi; else u1 |= 1ull<<(bi-64);
            idxb[b*5+k] = bi;
            if (bi < 6) n0 += 1.f;
        }
        n0f[b] = n0;
    }
}

// ---------------------------------------------------------------------------
// Grouped idx conv ks=15 + bias(n0*gb0) + leaky + maxpool4
// -> zp[128,64,508] f32.  Block = (b, qc of 4), 256 thr.
// ---------------------------------------------------------------------------
__global__ __launch_bounds__(256) void k_gconv(const float* __restrict__ x,
        const int* __restrict__ idxb, const float* __restrict__ n0f,
        const float* __restrict__ gw, const float* __restrict__ gb0,
        float* __restrict__ zp)
{
    __shared__ float xs[5][522];
    int b = blockIdx.x >> 2, qc = blockIdx.x & 3;
    int tid = threadIdx.x;
    int l0 = qc*508;
    for (int j=tid; j<5*522; j+=256){
        int k = j/522, u = j - k*522;
        int n = idxb[b*5+k];
        xs[k][u] = x[(size_t)b*196608 + n*2048 + l0 + u];
    }
    __syncthreads();
    int o = tid >> 2, qs = tid & 3;
    float wreg[5][15];
    #pragma unroll
    for (int k=0;k<5;k++){
        int n = idxb[b*5+k]; int gi = n/6;
        const float* wp = gw + gi*960 + o*15;
        #pragma unroll
        for (int s=0;s<15;s++) wreg[k][s] = wp[s];
    }
    float bv = n0f[b]*gb0[o];
    for (int q=qs; q<127; q+=4){
        int lb = 4*q;
        float s0=bv, s1=bv, s2=bv, s3=bv;
        #pragma unroll
        for (int k=0;k<5;k++){
            float xw[18];
            #pragma unroll
            for (int j=0;j<18;j++) xw[j] = xs[k][lb+j];
            #pragma unroll
            for (int sp=0;sp<15;sp++){
                s0 += wreg[k][sp]*xw[sp];
                s1 += wreg[k][sp]*xw[sp+1];
                s2 += wreg[k][sp]*xw[sp+2];
                s3 += wreg[k][sp]*xw[sp+3];
            }
        }
        float mx = fmaxf(fmaxf(lk(s0),lk(s1)), fmaxf(lk(s2),lk(s3)));
        zp[((size_t)(b*64+o))*508 + qc*127 + q] = mx;
    }
}

// ---------------------------------------------------------------------------
// Encoder conv2 ks=7 valid + leaky + maxpool4: zp[128,64,508] ->
// p2[128,128,125].  Thread = (b, oq of 64 [2 ch], qg of 25 [20 pos]).
// Grid 800 blocks.
// ---------------------------------------------------------------------------
__global__ __launch_bounds__(256) void k_econv2(const float* __restrict__ in,
        const float* __restrict__ w, const float* __restrict__ bias,
        float* __restrict__ p2)
{
    int g = blockIdx.x*256 + threadIdx.x;
    int qg = g % 25; int rest = g / 25; int oq = rest & 63; int b = rest >> 6;
    int l0 = qg*20;
    float acc[2][20];
    #pragma unroll
    for (int u=0;u<2;u++)
        #pragma unroll
        for (int i=0;i<20;i++) acc[u][i]=0.f;
    for (int ic=0; ic<64; ic++){
        const float* xc = in + ((size_t)(b*64+ic))*508 + l0;
        float xr[26];
        #pragma unroll
        for (int j=0;j<26;j++) xr[j] = xc[j];
        float wr[2][7];
        #pragma unroll
        for (int u=0;u<2;u++)
            #pragma unroll
            for (int s=0;s<7;s++) wr[u][s] = w[(((oq*2+u)*64)+ic)*7+s];
        #pragma unroll
        for (int u=0;u<2;u++)
            #pragma unroll
            for (int s=0;s<7;s++)
                #pragma unroll
                for (int l=0;l<20;l++) acc[u][l] += wr[u][s]*xr[l+s];
    }
    #pragma unroll
    for (int u=0;u<2;u++){
        int o = oq*2+u;
        float bv = bias[o];
        float* op = p2 + ((size_t)(b*128+o))*125 + qg*5;
        #pragma unroll
        for (int q=0;q<5;q++){
            float mx = -3.4e38f;
            #pragma unroll
            for (int j=0;j<4;j++) mx = fmaxf(mx, lk(acc[u][4*q+j]+bv));
            op[q] = mx;
        }
    }
}

// ---------------------------------------------------------------------------
// Sliding column sums: ssum[b,ic,s] = sum_{l=0..118} p2[b,ic,l+s], s=0..6
// ---------------------------------------------------------------------------
__global__ __launch_bounds__(256) void k_colsum(const float* __restrict__ p2,
        float* __restrict__ ssum)
{
    int g = blockIdx.x*256 + threadIdx.x;   // 16384 threads = (b,ic)
    int ic = g & 127, b = g >> 7;
    const float* pp = p2 + ((size_t)(b*128+ic))*125;
    float c = 0.f;
    for (int t=0;t<119;t++) c += pp[t];
    float* op = ssum + (size_t)(b*128+ic)*7;
    op[0] = c;
    #pragma unroll
    for (int s=0;s<6;s++){ c = c - pp[s] + pp[s+119]; op[s+1] = c; }
}

// ---------------------------------------------------------------------------
// feat[b,o] = eb3[o] + (1/119) * sum_{ic,s} ew3[o,ic,s]*ssum[b,ic,s]
// ---------------------------------------------------------------------------
__global__ __launch_bounds__(128) void k_feat(const float* __restrict__ ssum,
        const float* __restrict__ w, const float* __restrict__ bias,
        float* __restrict__ feat)
{
    __shared__ float ss[896];
    int b = blockIdx.x, o = threadIdx.x;
    for (int j=threadIdx.x; j<896; j+=128) ss[j] = ssum[(size_t)b*896 + j];
    __syncthreads();
    const float* wp = w + o*896;
    float s = 0.f;
    for (int j=0;j<896;j++) s += wp[j]*ss[j];
    feat[b*128+o] = s*(1.f/119.f) + bias[o];
}

// ---------------------------------------------------------------------------
// classifier + log_softmax -> out f32 [128,5]
// ---------------------------------------------------------------------------
__global__ __launch_bounds__(64) void k_cls(const float* __restrict__ feat,
        const float* __restrict__ cw, const float* __restrict__ cb,
        float* __restrict__ out)
{
    __shared__ float lg[5];
    int b = blockIdx.x;
    if (threadIdx.x < 5){
        const float* fp = feat + b*128;
        const float* wp = cw + threadIdx.x*128;
        float s = 0.f;
        for (int o=0;o<128;o++) s += fp[o]*wp[o];
        lg[threadIdx.x] = s + cb[threadIdx.x];
    }
    __syncthreads();
    if (threadIdx.x == 0){
        float mx = -3.4e38f;
        for (int c=0;c<5;c++) mx = fmaxf(mx, lg[c]);
        float se = 0.f;
        for (int c=0;c<5;c++) se += expf(lg[c]-mx);
        float lse = mx + logf(se);
        for (int c=0;c<5;c++) out[b*5+c] = lg[c]-lse;
    }
}

extern "C" void kernel_launch(void* const* d_in, const int* in_sizes, int n_in,
                              void* d_out, int out_size, void* d_ws, size_t ws_size,
                              hipStream_t stream)
{
    const float* x   = (const float*)d_in[0];
    const float* hw1 = (const float*)d_in[2];
    const float* hb1 = (const float*)d_in[3];
    const float* hw2 = (const float*)d_in[4];
    const float* hb2 = (const float*)d_in[5];
    const float* hw3 = (const float*)d_in[6];
    const float* hb3 = (const float*)d_in[7];
    const float* hl1 = (const float*)d_in[8];
    const float* hl2 = (const float*)d_in[9];
    const float* gw  = (const float*)d_in[10];
    const float* gb0 = (const float*)d_in[11];
    const float* ew2 = (const float*)d_in[12];
    const float* eb2 = (const float*)d_in[13];
    const float* ew3 = (const float*)d_in[14];
    const float* eb3 = (const float*)d_in[15];
    const float* cw  = (const float*)d_in[16];
    const float* cb  = (const float*)d_in[17];
    float* out = (float*)d_out;

    size_t wsf = ws_size / sizeof(float);
    // pick hypernet batch-chunking by available workspace
    int nch;
    if      (wsf >= 22806528 + 4096) nch = 1;   // 91.2 MB
    else if (wsf >= 16515072 + 4096) nch = 2;   // 66.1 MB
    else if (wsf >= 13369344 + 4096) nch = 4;   // 53.5 MB
    else                             nch = -1;  // round-2 fallback (40.9 MB)

    float* f = (float*)d_ws;
    if (nch > 0){
        // layout (floats):
        //   latent  @ 0          (786,432)
        //   partial @ 786,432    (3,145,728)  -> ends 3,932,160   [dead after hconv3b]
        //   h2      @ 3,932,160  (6,291,456)  -> ends 10,223,616  [dead after hconv3a]
        //   h1buf   @ 10,223,616 (12,582,912/nch)
        //   tail overlays partial/h2: t1 @ 786,432; idxb/n0f; zp; p2; ssum; feat
        float* latent  = f;
        float* partial = f + 786432;
        float* h2      = f + 3932160;
        float* h1buf   = f + 10223616;
        float* t1      = f + 786432;
        int*   idxb    = (int*)(f + 806432);
        float* n0f     = f + 808432;
        float* zp      = f + 810000;     // 4,161,536 -> ends 4,971,536
        float* p2      = f + 5000000;    // 2,048,000 -> ends 7,048,000
        float* ssum    = f + 7100000;    //   114,688
        float* feat    = f + 7300000;    //    16,384

        int bs = 128 / nch;
        for (int c = 0; c < nch; c++){
            const float* xc = x + (size_t)c*bs*16*12288;
            k_hconv1<<<bs*24, 256, 0, stream>>>(xc, hw1, hb1, h1buf);
            k_hconv2<<<bs*12, 256, 0, stream>>>(h1buf, hw2, hb2, h2 + (size_t)c*bs*64*768);
        }
        k_hconv3a<<<1536, 256, 0, stream>>>(h2, hw3, partial);
        k_hconv3b<<<3072, 256, 0, stream>>>(partial, hb3, latent);
        k_lin1<<<12288, 64, 0, stream>>>(latent, hl1, t1);
        k_topk<<<128, 128, 0, stream>>>(t1, hl2, idxb, n0f);
        k_gconv<<<512, 256, 0, stream>>>(x, idxb, n0f, gw, gb0, zp);
        k_econv2<<<800, 256, 0, stream>>>(zp, ew2, eb2, p2);
        k_colsum<<<64, 256, 0, stream>>>(p2, ssum);
        k_feat<<<128, 128, 0, stream>>>(ssum, ew3, eb3, feat);
        k_cls<<<128, 64, 0, stream>>>(feat, cw, cb, out);
    } else {
        // round-2 proven fallback (4 chunks, single-stage conv3)
        float* h2     = f;
        float* h1buf  = f + 6291456;
        float* latent = f + 9437184;
        float* t1     = f;
        int*   idxb   = (int*)(f + 20000);
        float* n0f    = f + 22000;
        float* zp     = f + 30000;
        float* p2     = f + 4200000;
        float* ssum   = f + 6300000;
        float* feat   = f + 6500000;

        for (int c = 0; c < 4; c++){
            const float* xc = x + (size_t)c*32*16*12288;
            float* h2c = h2 + (size_t)c*32*64*768;
            k_hconv1<<<768, 256, 0, stream>>>(xc, hw1, hb1, h1buf);
            k_hconv2<<<384, 256, 0, stream>>>(h1buf, hw2, hb2, h2c);
        }
        k_hconv3<<<384, 256, 0, stream>>>(h2, hw3, hb3, latent);
        k_lin1<<<12288, 64, 0, stream>>>(latent, hl1, t1);
        k_topk<<<128, 128, 0, stream>>>(t1, hl2, idxb, n0f);
        k_gconv<<<512, 256, 0, stream>>>(x, idxb, n0f, gw, gb0, zp);
        k_econv2<<<800, 256, 0, stream>>>(zp, ew2, eb2, p2);
        k_colsum<<<64, 256, 0, stream>>>(p2, ssum);
        k_feat<<<128, 128, 0, stream>>>(ssum, ew3, eb3, feat);
        k_cls<<<128, 64, 0, stream>>>(feat, cw, cb, out);
    }
}

// Round 4
// 917.928 us; speedup vs baseline: 2.0692x; 1.7724x over previous
//
#include <hip/hip_runtime.h>
#include <hip/hip_bf16.h>
#include <math.h>

__device__ __forceinline__ float lk(float v){ return v >= 0.f ? v : 0.01f*v; }

// ---------------------------------------------------------------------------
// Hypernet conv1, LDS-tiled: x[128,16,12288] f32, w[32,16,7], reflect-same,
// leaky, meanpool4 -> h1[128,32,3072] f32.
// Block = (b, tile of 768 conv pos). 256 thr = 32 o x 8 pos-slices (96 pos).
// LDS: 16 rows, stride 776 = 49.7 KB.
// ---------------------------------------------------------------------------
__global__ __launch_bounds__(256) void k_hconv1(const float* __restrict__ x,
        const float* __restrict__ w, const float* __restrict__ bias,
        float* __restrict__ out)
{
    __shared__ float xs[16*776];
    int b = blockIdx.x >> 4, tile = blockIdx.x & 15;
    int tid = threadIdx.x;
    int g0 = tile*768;
    const float* xb = x + (size_t)b*16*12288;
    for (int idx = tid; idx < 16*774; idx += 256){
        int ic = idx / 774, jj = idx - ic*774;
        int t = g0 + jj - 3;
        t = t < 0 ? -t : (t >= 12288 ? 2*12288-2-t : t);
        xs[ic*776 + jj] = xb[ic*12288 + t];
    }
    __syncthreads();
    int o = tid & 31, s = tid >> 5;
    float bv = bias[o];
    // conv sums for this thread's 96 positions, chunked 16 at a time;
    // acc = pooled mean accumulation (sum of leaky, scaled at end)
    float acc[24];
    #pragma unroll
    for (int i=0;i<24;i++) acc[i]=0.f;
    float cs[96];
    #pragma unroll
    for (int i=0;i<96;i++) cs[i]=bv;
    for (int ic=0; ic<16; ic++){
        const float* wp = w + (o*16+ic)*7;
        float wr[7];
        #pragma unroll
        for (int t=0;t<7;t++) wr[t] = wp[t];
        const float* xrow = xs + ic*776 + s*96;
        #pragma unroll
        for (int c=0;c<6;c++){
            const float4* xq = reinterpret_cast<const float4*>(xrow + c*16);
            float4 a0=xq[0], a1=xq[1], a2=xq[2], a3=xq[3], a4=xq[4], a5=xq[5];
            float xw[24] = {a0.x,a0.y,a0.z,a0.w, a1.x,a1.y,a1.z,a1.w,
                            a2.x,a2.y,a2.z,a2.w, a3.x,a3.y,a3.z,a3.w,
                            a4.x,a4.y,a4.z,a4.w, a5.x,a5.y,a5.z,a5.w};
            #pragma unroll
            for (int p=0;p<16;p++){
                float sv = cs[c*16+p];
                #pragma unroll
                for (int t=0;t<7;t++) sv += wr[t]*xw[p+t];
                cs[c*16+p] = sv;
            }
        }
    }
    #pragma unroll
    for (int p=0;p<96;p++) acc[p>>2] += lk(cs[p]);
    float* op = out + ((size_t)(b*32+o))*3072 + tile*192 + s*24;
    #pragma unroll
    for (int k=0;k<24;k++) op[k] = acc[k]*0.25f;
}

// ---------------------------------------------------------------------------
// Hypernet conv2, LDS-tiled: h1[128,32,3072] f32, w[64,32,7], reflect-same,
// leaky, meanpool4 -> h2[128,64,768] f32.
// Block = (b, tile of 384 pos). 256 thr = 64 o x 4 slices (96 pos).
// LDS: 32 rows, stride 392 = 49.2 KB.
// ---------------------------------------------------------------------------
__global__ __launch_bounds__(256) void k_hconv2(const float* __restrict__ in,
        const float* __restrict__ w, const float* __restrict__ bias,
        float* __restrict__ out)
{
    __shared__ float xs[32*392];
    int b = blockIdx.x >> 3, tile = blockIdx.x & 7;
    int tid = threadIdx.x;
    int g0 = tile*384;
    const float* xb = in + (size_t)b*32*3072;
    for (int idx = tid; idx < 32*390; idx += 256){
        int ic = idx / 390, jj = idx - ic*390;
        int t = g0 + jj - 3;
        t = t < 0 ? -t : (t >= 3072 ? 2*3072-2-t : t);
        xs[ic*392 + jj] = xb[ic*3072 + t];
    }
    __syncthreads();
    int o = tid & 63, s = tid >> 6;
    float bv = bias[o];
    float cs[96];
    #pragma unroll
    for (int i=0;i<96;i++) cs[i]=bv;
    for (int ic=0; ic<32; ic++){
        const float* wp = w + (o*32+ic)*7;
        float wr[7];
        #pragma unroll
        for (int t=0;t<7;t++) wr[t] = wp[t];
        const float* xrow = xs + ic*392 + s*96;
        #pragma unroll
        for (int c=0;c<6;c++){
            const float4* xq = reinterpret_cast<const float4*>(xrow + c*16);
            float4 a0=xq[0], a1=xq[1], a2=xq[2], a3=xq[3], a4=xq[4], a5=xq[5];
            float xw[24] = {a0.x,a0.y,a0.z,a0.w, a1.x,a1.y,a1.z,a1.w,
                            a2.x,a2.y,a2.z,a2.w, a3.x,a3.y,a3.z,a3.w,
                            a4.x,a4.y,a4.z,a4.w, a5.x,a5.y,a5.z,a5.w};
            #pragma unroll
            for (int p=0;p<16;p++){
                float sv = cs[c*16+p];
                #pragma unroll
                for (int t=0;t<7;t++) sv += wr[t]*xw[p+t];
                cs[c*16+p] = sv;
            }
        }
    }
    float acc[24];
    #pragma unroll
    for (int i=0;i<24;i++) acc[i]=0.f;
    #pragma unroll
    for (int p=0;p<96;p++) acc[p>>2] += lk(cs[p]);
    float* op = out + ((size_t)(b*64+o))*768 + tile*96 + s*24;
    #pragma unroll
    for (int k=0;k<24;k++) op[k] = acc[k]*0.25f;
}

// ---------------------------------------------------------------------------
// Hypernet conv3 stage A: ic-split partial sums (4 groups of 16 ic).
// ---------------------------------------------------------------------------
__global__ __launch_bounds__(256) void k_hconv3a(const float* __restrict__ in,
        const float* __restrict__ w, float* __restrict__ partial)
{
    int g = blockIdx.x*256 + threadIdx.x;
    int ug = g % 96; int r = g / 96;
    int c = r & 7; int b = (r >> 3) & 127; int icq = r >> 10;
    int t0 = ug*8 - 3;
    int tt[14];
    #pragma unroll
    for (int j=0;j<14;j++){ int t=t0+j; tt[j] = t<0 ? -t : (t>=768 ? 2*768-2-t : t); }
    float acc[8];
    #pragma unroll
    for (int i=0;i<8;i++) acc[i]=0.f;
    for (int ic=icq*16; ic<icq*16+16; ic++){
        const float* xc = in + ((size_t)(b*64+ic))*768;
        float xr[14];
        #pragma unroll
        for (int j=0;j<14;j++) xr[j] = xc[tt[j]];
        const float* wp = w + (c*64+ic)*7;
        float wr[7];
        #pragma unroll
        for (int s=0;s<7;s++) wr[s] = wp[s];
        #pragma unroll
        for (int s=0;s<7;s++)
            #pragma unroll
            for (int l=0;l<8;l++) acc[l] += wr[s]*xr[l+s];
    }
    float* op = partial + ((size_t)(icq*1024 + b*8 + c))*768 + ug*8;
    #pragma unroll
    for (int l=0;l<8;l++) op[l] = acc[l];
}

// ---------------------------------------------------------------------------
// Hypernet conv3 stage B: combine partials + bias + tanh -> latent[128,6144]
// ---------------------------------------------------------------------------
__global__ __launch_bounds__(256) void k_hconv3b(const float* __restrict__ partial,
        const float* __restrict__ bias, float* __restrict__ latent)
{
    int idx = blockIdx.x*256 + threadIdx.x;   // 786432 total
    int pos = idx % 768; int r = idx / 768;
    int c = r & 7; int b = r >> 3;
    float s = bias[c];
    #pragma unroll
    for (int q=0;q<4;q++) s += partial[((size_t)(q*1024 + b*8 + c))*768 + pos];
    latent[(size_t)b*6144 + c*768 + pos] = tanhf(s);
}

// ---------------------------------------------------------------------------
// t1 = leaky(latent @ hl1^T): one wave per (b,n); dot over 6144.
// ---------------------------------------------------------------------------
__global__ __launch_bounds__(64) void k_lin1(const float* __restrict__ latent,
        const float* __restrict__ hl1, float* __restrict__ t1)
{
    int b = blockIdx.x / 96, n = blockIdx.x % 96;
    int lane = threadIdx.x;
    const float* lp = latent + (size_t)b*6144;
    const float* wp = hl1 + (size_t)n*6144;
    float s = 0.f;
    for (int i=lane; i<6144; i+=64) s += lp[i]*wp[i];
    #pragma unroll
    for (int off=32; off; off>>=1) s += __shfl_down(s, off);
    if (lane==0) t1[b*96+n] = lk(s);
}

// ---------------------------------------------------------------------------
// logits = t1 @ hl2^T; top-5 (descending, ties -> lower index); n0 = #(idx<6)
// ---------------------------------------------------------------------------
__global__ __launch_bounds__(128) void k_topk(const float* __restrict__ t1,
        const float* __restrict__ hl2, int* __restrict__ idxb, float* __restrict__ n0f)
{
    __shared__ float lg[96];
    int b = blockIdx.x, n = threadIdx.x;
    if (n < 96){
        float s = 0.f;
        const float* tp = t1 + b*96;
        const float* wp = hl2 + n*96;
        for (int m=0;m<96;m++) s += tp[m]*wp[m];
        lg[n] = s;
    }
    __syncthreads();
    if (threadIdx.x == 0){
        unsigned long long u0=0ull, u1=0ull;
        float n0 = 0.f;
        for (int k=0;k<5;k++){
            float best = -3.4e38f; int bi = 0;
            for (int m=0;m<96;m++){
                bool used = m<64 ? ((u0>>m)&1ull) : ((u1>>(m-64))&1ull);
                if (!used && lg[m] > best){ best = lg[m]; bi = m; }
            }
            if (bi<64) u0 |= 1ull<<bi; else u1 |= 1ull<<(bi-64);
            idxb[b*5+k] = bi;
            if (bi < 6) n0 += 1.f;
        }
        n0f[b] = n0;
    }
}

// ---------------------------------------------------------------------------
// Grouped idx conv ks=15 + bias(n0*gb0) + leaky + maxpool4
// -> zp[128,64,508] f32.  Block = (b, qc of 4), 256 thr.
// ---------------------------------------------------------------------------
__global__ __launch_bounds__(256) void k_gconv(const float* __restrict__ x,
        const int* __restrict__ idxb, const float* __restrict__ n0f,
        const float* __restrict__ gw, const float* __restrict__ gb0,
        float* __restrict__ zp)
{
    __shared__ float xs[5][522];
    int b = blockIdx.x >> 2, qc = blockIdx.x & 3;
    int tid = threadIdx.x;
    int l0 = qc*508;
    for (int j=tid; j<5*522; j+=256){
        int k = j/522, u = j - k*522;
        int n = idxb[b*5+k];
        xs[k][u] = x[(size_t)b*196608 + n*2048 + l0 + u];
    }
    __syncthreads();
    int o = tid >> 2, qs = tid & 3;
    float wreg[5][15];
    #pragma unroll
    for (int k=0;k<5;k++){
        int n = idxb[b*5+k]; int gi = n/6;
        const float* wp = gw + gi*960 + o*15;
        #pragma unroll
        for (int s=0;s<15;s++) wreg[k][s] = wp[s];
    }
    float bv = n0f[b]*gb0[o];
    for (int q=qs; q<127; q+=4){
        int lb = 4*q;
        float s0=bv, s1=bv, s2=bv, s3=bv;
        #pragma unroll
        for (int k=0;k<5;k++){
            float xw[18];
            #pragma unroll
            for (int j=0;j<18;j++) xw[j] = xs[k][lb+j];
            #pragma unroll
            for (int sp=0;sp<15;sp++){
                s0 += wreg[k][sp]*xw[sp];
                s1 += wreg[k][sp]*xw[sp+1];
                s2 += wreg[k][sp]*xw[sp+2];
                s3 += wreg[k][sp]*xw[sp+3];
            }
        }
        float mx = fmaxf(fmaxf(lk(s0),lk(s1)), fmaxf(lk(s2),lk(s3)));
        zp[((size_t)(b*64+o))*508 + qc*127 + q] = mx;
    }
}

// ---------------------------------------------------------------------------
// Encoder conv2, LDS-tiled: zp[128,64,508] f32, w[128,64,7] valid, leaky,
// maxpool4 -> p2[128,128,125].
// Block = (b, tile of 25 pooled = 100 conv pos). 128 thr = 128 o.
// LDS: 64 rows, stride 108 = 27.6 KB.  Conv sums kept across full ic loop,
// leaky+maxpool applied after.
// ---------------------------------------------------------------------------
__global__ __launch_bounds__(128) void k_econv2(const float* __restrict__ in,
        const float* __restrict__ w, const float* __restrict__ bias,
        float* __restrict__ p2)
{
    __shared__ float xs[64*108];
    int b = blockIdx.x / 5, tt = blockIdx.x % 5;
    int tid = threadIdx.x;
    const float* zb = in + (size_t)b*64*508 + tt*100;
    for (int idx = tid; idx < 64*106; idx += 128){
        int ic = idx / 106, jj = idx - ic*106;
        xs[ic*108 + jj] = zb[ic*508 + jj];
    }
    __syncthreads();
    int o = tid;
    float bv = bias[o];
    float cs[100];
    #pragma unroll
    for (int i=0;i<100;i++) cs[i]=bv;
    for (int ic=0; ic<64; ic++){
        const float* wp = w + (o*64+ic)*7;
        float wr[7];
        #pragma unroll
        for (int t=0;t<7;t++) wr[t] = wp[t];
        const float* xrow = xs + ic*108;
        #pragma unroll
        for (int c=0;c<5;c++){
            const float4* xq = reinterpret_cast<const float4*>(xrow + c*20);
            float4 a0=xq[0], a1=xq[1], a2=xq[2], a3=xq[3], a4=xq[4], a5=xq[5], a6=xq[6];
            float xw[28] = {a0.x,a0.y,a0.z,a0.w, a1.x,a1.y,a1.z,a1.w,
                            a2.x,a2.y,a2.z,a2.w, a3.x,a3.y,a3.z,a3.w,
                            a4.x,a4.y,a4.z,a4.w, a5.x,a5.y,a5.z,a5.w,
                            a6.x,a6.y,a6.z,a6.w};
            #pragma unroll
            for (int p=0;p<20;p++){
                float sv = cs[c*20+p];
                #pragma unroll
                for (int t=0;t<7;t++) sv += wr[t]*xw[p+t];
                cs[c*20+p] = sv;
            }
        }
    }
    float* op = p2 + ((size_t)(b*128+o))*125 + tt*25;
    #pragma unroll
    for (int k=0;k<25;k++){
        float mx = -3.4e38f;
        #pragma unroll
        for (int j=0;j<4;j++) mx = fmaxf(mx, lk(cs[k*4+j]));
        op[k] = mx;
    }
}

// ---------------------------------------------------------------------------
// Sliding column sums: ssum[b,ic,s] = sum_{l=0..118} p2[b,ic,l+s], s=0..6
// ---------------------------------------------------------------------------
__global__ __launch_bounds__(256) void k_colsum(const float* __restrict__ p2,
        float* __restrict__ ssum)
{
    int g = blockIdx.x*256 + threadIdx.x;   // 16384 threads = (b,ic)
    int ic = g & 127, b = g >> 7;
    const float* pp = p2 + ((size_t)(b*128+ic))*125;
    float c = 0.f;
    for (int t=0;t<119;t++) c += pp[t];
    float* op = ssum + (size_t)(b*128+ic)*7;
    op[0] = c;
    #pragma unroll
    for (int s=0;s<6;s++){ c = c - pp[s] + pp[s+119]; op[s+1] = c; }
}

// ---------------------------------------------------------------------------
// feat[b,o] = eb3[o] + (1/119) * sum_{ic,s} ew3[o,ic,s]*ssum[b,ic,s]
// ---------------------------------------------------------------------------
__global__ __launch_bounds__(128) void k_feat(const float* __restrict__ ssum,
        const float* __restrict__ w, const float* __restrict__ bias,
        float* __restrict__ feat)
{
    __shared__ float ss[896];
    int b = blockIdx.x, o = threadIdx.x;
    for (int j=threadIdx.x; j<896; j+=128) ss[j] = ssum[(size_t)b*896 + j];
    __syncthreads();
    const float* wp = w + o*896;
    float s = 0.f;
    for (int j=0;j<896;j++) s += wp[j]*ss[j];
    feat[b*128+o] = s*(1.f/119.f) + bias[o];
}

// ---------------------------------------------------------------------------
// classifier + log_softmax -> out f32 [128,5]
// ---------------------------------------------------------------------------
__global__ __launch_bounds__(64) void k_cls(const float* __restrict__ feat,
        const float* __restrict__ cw, const float* __restrict__ cb,
        float* __restrict__ out)
{
    __shared__ float lg[5];
    int b = blockIdx.x;
    if (threadIdx.x < 5){
        const float* fp = feat + b*128;
        const float* wp = cw + threadIdx.x*128;
        float s = 0.f;
        for (int o=0;o<128;o++) s += fp[o]*wp[o];
        lg[threadIdx.x] = s + cb[threadIdx.x];
    }
    __syncthreads();
    if (threadIdx.x == 0){
        float mx = -3.4e38f;
        for (int c=0;c<5;c++) mx = fmaxf(mx, lg[c]);
        float se = 0.f;
        for (int c=0;c<5;c++) se += expf(lg[c]-mx);
        float lse = mx + logf(se);
        for (int c=0;c<5;c++) out[b*5+c] = lg[c]-lse;
    }
}

extern "C" void kernel_launch(void* const* d_in, const int* in_sizes, int n_in,
                              void* d_out, int out_size, void* d_ws, size_t ws_size,
                              hipStream_t stream)
{
    const float* x   = (const float*)d_in[0];
    const float* hw1 = (const float*)d_in[2];
    const float* hb1 = (const float*)d_in[3];
    const float* hw2 = (const float*)d_in[4];
    const float* hb2 = (const float*)d_in[5];
    const float* hw3 = (const float*)d_in[6];
    const float* hb3 = (const float*)d_in[7];
    const float* hl1 = (const float*)d_in[8];
    const float* hl2 = (const float*)d_in[9];
    const float* gw  = (const float*)d_in[10];
    const float* gb0 = (const float*)d_in[11];
    const float* ew2 = (const float*)d_in[12];
    const float* eb2 = (const float*)d_in[13];
    const float* ew3 = (const float*)d_in[14];
    const float* eb3 = (const float*)d_in[15];
    const float* cw  = (const float*)d_in[16];
    const float* cb  = (const float*)d_in[17];
    float* out = (float*)d_out;

    // layout (floats) — 91.2 MB peak, proven to fit in round 3 (nch=1 ran):
    //   latent @0 (786,432) | partial @786,432 (3,145,728) | h2 @3,932,160
    //   (6,291,456) | h1 @10,223,616 (12,582,912)
    //   tail overlays partial/h2: t1, idxb, n0f, zp, p2, ssum, feat
    float* f       = (float*)d_ws;
    float* latent  = f;
    float* partial = f + 786432;
    float* h2      = f + 3932160;
    float* h1      = f + 10223616;
    float* t1      = f + 786432;
    int*   idxb    = (int*)(f + 806432);
    float* n0f     = f + 808432;
    float* zp      = f + 810000;
    float* p2      = f + 5000000;
    float* ssum    = f + 7100000;
    float* feat    = f + 7300000;

    k_hconv1<<<2048, 256, 0, stream>>>(x, hw1, hb1, h1);
    k_hconv2<<<1024, 256, 0, stream>>>(h1, hw2, hb2, h2);
    k_hconv3a<<<1536, 256, 0, stream>>>(h2, hw3, partial);
    k_hconv3b<<<3072, 256, 0, stream>>>(partial, hb3, latent);
    k_lin1<<<12288, 64, 0, stream>>>(latent, hl1, t1);
    k_topk<<<128, 128, 0, stream>>>(t1, hl2, idxb, n0f);
    k_gconv<<<512, 256, 0, stream>>>(x, idxb, n0f, gw, gb0, zp);
    k_econv2<<<640, 128, 0, stream>>>(zp, ew2, eb2, p2);
    k_colsum<<<64, 256, 0, stream>>>(p2, ssum);
    k_feat<<<128, 128, 0, stream>>>(ssum, ew3, eb3, feat);
    k_cls<<<128, 64, 0, stream>>>(feat, cw, cb, out);
}

// Round 5
// 822.249 us; speedup vs baseline: 2.3100x; 1.1164x over previous
//
#include <hip/hip_runtime.h>
#include <hip/hip_bf16.h>
#include <math.h>

typedef unsigned short u16;
typedef __attribute__((ext_vector_type(8))) short short8;
typedef __attribute__((ext_vector_type(4))) float floatx4;

__device__ __forceinline__ float lk(float v){ return v >= 0.f ? v : 0.01f*v; }
__device__ __forceinline__ u16 f2b(float f){
    __hip_bfloat16 h = __float2bfloat16(f);
    return *reinterpret_cast<u16*>(&h);
}
__device__ __forceinline__ float b2f(u16 u){
    union { unsigned u; float f; } c; c.u = ((unsigned)u) << 16; return c.f;
}

// ---------------------------------------------------------------------------
// Hypernet conv1 (MFMA bf16): x[128,16,12288] f32, w[32,16,7], reflect-same,
// leaky, meanpool4 -> h1 bf16 [128,32,3072].
// GEMM: C[o,t] = sum_{k=ic*?+tap} A[o,k]*B[k,t].  k-step s of 32:
//   tap = 2s + (kq>>1), ic = (kq&1)*8 + j   (s=3,kq>=2 -> tap=7 zero-pad A)
// Block = (b, tile of 512 pos); 4 waves = (ohalf x thalf-256).
// LDS xs[tloc][ic] bf16, stride 24 (48B), 520 rows.
// ---------------------------------------------------------------------------
__global__ __launch_bounds__(256) void k_hconv1(const float* __restrict__ x,
        const float* __restrict__ w, const float* __restrict__ bias,
        u16* __restrict__ h1)
{
    __shared__ __align__(16) u16 xs[520*24];
    int b = blockIdx.x / 24, tile = blockIdx.x % 24;
    int g0 = tile*512;
    int tid = threadIdx.x;
    const float* xb = x + (size_t)b*16*12288;
    for (int row = tid; row < 520; row += 256){
        int t = g0 + row - 3;
        t = t < 0 ? -t : (t >= 12288 ? 2*12288-2-t : t);
        u16 v[16];
        #pragma unroll
        for (int ic=0;ic<16;ic++) v[ic] = f2b(xb[(size_t)ic*12288 + t]);
        short8 p0, p1;
        #pragma unroll
        for (int j=0;j<8;j++){ p0[j] = (short)v[j]; p1[j] = (short)v[8+j]; }
        *reinterpret_cast<short8*>(&xs[row*24])     = p0;
        *reinterpret_cast<short8*>(&xs[row*24 + 8]) = p1;
    }
    __syncthreads();
    int wv = tid >> 6, lane = tid & 63;
    int m = lane & 15, kq = lane >> 4;
    int ohalf = wv & 1, thalf = wv >> 1;
    int o = ohalf*16 + m;
    short8 afr[4];
    #pragma unroll
    for (int s=0;s<4;s++){
        int tap = 2*s + (kq>>1);
        #pragma unroll
        for (int j=0;j<8;j++){
            int ic = (kq&1)*8 + j;
            afr[s][j] = (tap < 7) ? (short)f2b(w[(o*16+ic)*7 + tap]) : (short)0;
        }
    }
    floatx4 acc[16];
    #pragma unroll
    for (int i=0;i<16;i++) acc[i] = (floatx4){0.f,0.f,0.f,0.f};
    int tb0 = thalf*256;
    #pragma unroll
    for (int sub=0; sub<16; sub++){
        int tb = tb0 + sub*16;
        #pragma unroll
        for (int s=0;s<4;s++){
            int tap = 2*s + (kq>>1);
            short8 bfr = *reinterpret_cast<const short8*>(
                            &xs[(tb + m + tap)*24 + (kq&1)*8]);
            acc[sub] = __builtin_amdgcn_mfma_f32_16x16x32_bf16(afr[s], bfr, acc[sub], 0,0,0);
        }
    }
    int ob = ohalf*16 + kq*4;
    float bv[4];
    #pragma unroll
    for (int r=0;r<4;r++) bv[r] = bias[ob + r];
    int n = lane & 15;
    bool wr = (lane & 3) == 0;
    #pragma unroll
    for (int sub=0; sub<16; sub++){
        int tg = g0 + tb0 + sub*16 + n;
        #pragma unroll
        for (int r=0;r<4;r++){
            float v = lk(acc[sub][r] + bv[r]);
            v += __shfl_xor(v, 1);
            v += __shfl_xor(v, 2);
            if (wr) h1[(size_t)(b*32 + ob + r)*3072 + (tg>>2)] = f2b(v*0.25f);
        }
    }
}

// ---------------------------------------------------------------------------
// Hypernet conv2 (MFMA bf16): h1 bf16 [128,32,3072], w[64,32,7], reflect-same,
// leaky, meanpool4 -> h2 f32 [128,64,768].
// k-step s = tap (7 steps), ic = kq*8+j (all 32 ic per step).
// Block = (b, tile of 384 pos); wave = o-tile of 16; 24 subtiles each.
// LDS xs[tloc][ic] bf16, stride 40 (80B), 390 rows.
// ---------------------------------------------------------------------------
__global__ __launch_bounds__(256,1) void k_hconv2(const u16* __restrict__ h1,
        const float* __restrict__ w, const float* __restrict__ bias,
        float* __restrict__ h2)
{
    __shared__ __align__(16) u16 xs[390*40];
    int b = blockIdx.x >> 3, tile = blockIdx.x & 7;
    int g0 = tile*384;
    int tid = threadIdx.x;
    for (int row = tid; row < 390; row += 256){
        int t = g0 + row - 3;
        t = t < 0 ? -t : (t >= 3072 ? 2*3072-2-t : t);
        u16 v[32];
        #pragma unroll
        for (int ic=0;ic<32;ic++) v[ic] = h1[(size_t)(b*32+ic)*3072 + t];
        #pragma unroll
        for (int q=0;q<4;q++){
            short8 p;
            #pragma unroll
            for (int j=0;j<8;j++) p[j] = (short)v[q*8+j];
            *reinterpret_cast<short8*>(&xs[row*40 + q*8]) = p;
        }
    }
    __syncthreads();
    int wv = tid >> 6, lane = tid & 63;
    int m = lane & 15, kq = lane >> 4;
    int o = wv*16 + m;
    short8 afr[7];
    #pragma unroll
    for (int s=0;s<7;s++){
        #pragma unroll
        for (int j=0;j<8;j++)
            afr[s][j] = (short)f2b(w[(size_t)(o*32 + kq*8 + j)*7 + s]);
    }
    floatx4 acc[24];
    #pragma unroll
    for (int i=0;i<24;i++) acc[i] = (floatx4){0.f,0.f,0.f,0.f};
    for (int sub=0; sub<24; sub++){
        int tb = sub*16;
        #pragma unroll
        for (int s=0;s<7;s++){
            short8 bfr = *reinterpret_cast<const short8*>(
                            &xs[(tb + m + s)*40 + kq*8]);
            acc[sub] = __builtin_amdgcn_mfma_f32_16x16x32_bf16(afr[s], bfr, acc[sub], 0,0,0);
        }
    }
    int ob = wv*16 + kq*4;
    float bv[4];
    #pragma unroll
    for (int r=0;r<4;r++) bv[r] = bias[ob + r];
    int n = lane & 15;
    bool wr = (lane & 3) == 0;
    #pragma unroll
    for (int sub=0; sub<24; sub++){
        int tg = g0 + sub*16 + n;
        #pragma unroll
        for (int r=0;r<4;r++){
            float v = lk(acc[sub][r] + bv[r]);
            v += __shfl_xor(v, 1);
            v += __shfl_xor(v, 2);
            if (wr) h2[(size_t)(b*64 + ob + r)*768 + (tg>>2)] = v*0.25f;
        }
    }
}

// ---------------------------------------------------------------------------
// Hypernet conv3 stage A: ic-split partial sums (fp32, unchanged).
// ---------------------------------------------------------------------------
__global__ __launch_bounds__(256) void k_hconv3a(const float* __restrict__ in,
        const float* __restrict__ w, float* __restrict__ partial)
{
    int g = blockIdx.x*256 + threadIdx.x;
    int ug = g % 96; int r = g / 96;
    int c = r & 7; int b = (r >> 3) & 127; int icq = r >> 10;
    int t0 = ug*8 - 3;
    int tt[14];
    #pragma unroll
    for (int j=0;j<14;j++){ int t=t0+j; tt[j] = t<0 ? -t : (t>=768 ? 2*768-2-t : t); }
    float acc[8];
    #pragma unroll
    for (int i=0;i<8;i++) acc[i]=0.f;
    for (int ic=icq*16; ic<icq*16+16; ic++){
        const float* xc = in + ((size_t)(b*64+ic))*768;
        float xr[14];
        #pragma unroll
        for (int j=0;j<14;j++) xr[j] = xc[tt[j]];
        const float* wp = w + (c*64+ic)*7;
        float wr[7];
        #pragma unroll
        for (int s=0;s<7;s++) wr[s] = wp[s];
        #pragma unroll
        for (int s=0;s<7;s++)
            #pragma unroll
            for (int l=0;l<8;l++) acc[l] += wr[s]*xr[l+s];
    }
    float* op = partial + ((size_t)(icq*1024 + b*8 + c))*768 + ug*8;
    #pragma unroll
    for (int l=0;l<8;l++) op[l] = acc[l];
}

__global__ __launch_bounds__(256) void k_hconv3b(const float* __restrict__ partial,
        const float* __restrict__ bias, float* __restrict__ latent)
{
    int idx = blockIdx.x*256 + threadIdx.x;
    int pos = idx % 768; int r = idx / 768;
    int c = r & 7; int b = r >> 3;
    float s = bias[c];
    #pragma unroll
    for (int q=0;q<4;q++) s += partial[((size_t)(q*1024 + b*8 + c))*768 + pos];
    latent[(size_t)b*6144 + c*768 + pos] = tanhf(s);
}

// ---------------------------------------------------------------------------
// t1 = leaky(latent @ hl1^T): block per b; latent staged once; coalesced w.
// ---------------------------------------------------------------------------
__global__ __launch_bounds__(256,1) void k_lin1(const float* __restrict__ latent,
        const float* __restrict__ hl1, float* __restrict__ t1)
{
    __shared__ float ls[6144];
    int b = blockIdx.x, tid = threadIdx.x;
    const float4* lp = reinterpret_cast<const float4*>(latent + (size_t)b*6144);
    float4* lsv = reinterpret_cast<float4*>(ls);
    for (int i = tid; i < 1536; i += 256) lsv[i] = lp[i];
    __syncthreads();
    int wv = tid >> 6, lane = tid & 63;
    float lr[96];
    #pragma unroll
    for (int j=0;j<24;j++){
        float4 q = lsv[lane + 64*j];
        lr[4*j]=q.x; lr[4*j+1]=q.y; lr[4*j+2]=q.z; lr[4*j+3]=q.w;
    }
    for (int nn=0; nn<24; nn++){
        int n = wv*24 + nn;
        const float4* wp = reinterpret_cast<const float4*>(hl1 + (size_t)n*6144);
        float s = 0.f;
        #pragma unroll
        for (int j=0;j<24;j++){
            float4 q = wp[lane + 64*j];
            s += lr[4*j]*q.x + lr[4*j+1]*q.y + lr[4*j+2]*q.z + lr[4*j+3]*q.w;
        }
        #pragma unroll
        for (int off=32; off; off>>=1) s += __shfl_down(s, off);
        if (lane==0) t1[b*96+n] = lk(s);
    }
}

// ---------------------------------------------------------------------------
// logits = t1 @ hl2^T; top-5; n0 = #(idx<6)   (unchanged)
// ---------------------------------------------------------------------------
__global__ __launch_bounds__(128) void k_topk(const float* __restrict__ t1,
        const float* __restrict__ hl2, int* __restrict__ idxb, float* __restrict__ n0f)
{
    __shared__ float lg[96];
    int b = blockIdx.x, n = threadIdx.x;
    if (n < 96){
        float s = 0.f;
        const float* tp = t1 + b*96;
        const float* wp = hl2 + n*96;
        for (int m=0;m<96;m++) s += tp[m]*wp[m];
        lg[n] = s;
    }
    __syncthreads();
    if (threadIdx.x == 0){
        unsigned long long u0=0ull, u1=0ull;
        float n0 = 0.f;
        for (int k=0;k<5;k++){
            float best = -3.4e38f; int bi = 0;
            for (int m=0;m<96;m++){
                bool used = m<64 ? ((u0>>m)&1ull) : ((u1>>(m-64))&1ull);
                if (!used && lg[m] > best){ best = lg[m]; bi = m; }
            }
            if (bi<64) u0 |= 1ull<<bi; else u1 |= 1ull<<(bi-64);
            idxb[b*5+k] = bi;
            if (bi < 6) n0 += 1.f;
        }
        n0f[b] = n0;
    }
}

// ---------------------------------------------------------------------------
// Grouped idx conv ks=15 + bias + leaky + maxpool4 -> zp bf16 [128,64,508]
// ---------------------------------------------------------------------------
__global__ __launch_bounds__(256) void k_gconv(const float* __restrict__ x,
        const int* __restrict__ idxb, const float* __restrict__ n0f,
        const float* __restrict__ gw, const float* __restrict__ gb0,
        u16* __restrict__ zp)
{
    __shared__ float xs[5][522];
    int b = blockIdx.x >> 2, qc = blockIdx.x & 3;
    int tid = threadIdx.x;
    int l0 = qc*508;
    for (int j=tid; j<5*522; j+=256){
        int k = j/522, u = j - k*522;
        int n = idxb[b*5+k];
        xs[k][u] = x[(size_t)b*196608 + n*2048 + l0 + u];
    }
    __syncthreads();
    int o = tid >> 2, qs = tid & 3;
    float wreg[5][15];
    #pragma unroll
    for (int k=0;k<5;k++){
        int n = idxb[b*5+k]; int gi = n/6;
        const float* wp = gw + gi*960 + o*15;
        #pragma unroll
        for (int s=0;s<15;s++) wreg[k][s] = wp[s];
    }
    float bv = n0f[b]*gb0[o];
    for (int q=qs; q<127; q+=4){
        int lb = 4*q;
        float s0=bv, s1=bv, s2=bv, s3=bv;
        #pragma unroll
        for (int k=0;k<5;k++){
            float xw[18];
            #pragma unroll
            for (int j=0;j<18;j++) xw[j] = xs[k][lb+j];
            #pragma unroll
            for (int sp=0;sp<15;sp++){
                s0 += wreg[k][sp]*xw[sp];
                s1 += wreg[k][sp]*xw[sp+1];
                s2 += wreg[k][sp]*xw[sp+2];
                s3 += wreg[k][sp]*xw[sp+3];
            }
        }
        float mx = fmaxf(fmaxf(lk(s0),lk(s1)), fmaxf(lk(s2),lk(s3)));
        zp[((size_t)(b*64+o))*508 + qc*127 + q] = f2b(mx);
    }
}

// ---------------------------------------------------------------------------
// Encoder conv2 (MFMA bf16): zp bf16 [128,64,508], w[128,64,7] VALID, leaky,
// maxpool4 -> p2 f32 [128,128,125].
// k-step s in 0..13: ic-half = s/7, tap = s%7; ic = ih*32 + kq*8 + j.
// Block = (b, tile of 100 conv pos); wave handles otiles {wv, wv+4}.
// LDS xs[tloc][ic] bf16, stride 72 (144B), 118 rows.
// ---------------------------------------------------------------------------
__global__ __launch_bounds__(256,1) void k_econv2(const u16* __restrict__ zp,
        const float* __restrict__ w, const float* __restrict__ bias,
        float* __restrict__ p2)
{
    __shared__ __align__(16) u16 xs[118*72];
    int b = blockIdx.x / 5, tile = blockIdx.x % 5;
    int tid = threadIdx.x;
    if (tid < 118){
        int t = tile*100 + tid; if (t > 507) t = 507;
        u16 v[64];
        #pragma unroll
        for (int ic=0;ic<64;ic++) v[ic] = zp[(size_t)(b*64+ic)*508 + t];
        #pragma unroll
        for (int q=0;q<8;q++){
            short8 p;
            #pragma unroll
            for (int j=0;j<8;j++) p[j] = (short)v[q*8+j];
            *reinterpret_cast<short8*>(&xs[tid*72 + q*8]) = p;
        }
    }
    __syncthreads();
    int wv = tid >> 6, lane = tid & 63;
    int m = lane & 15, kq = lane >> 4;
    int n = lane & 15;
    bool wrm = (lane & 3) == 0;
    for (int half=0; half<2; half++){
        int ot = wv + 4*half;
        int o = ot*16 + m;
        short8 afr[14];
        #pragma unroll
        for (int s=0;s<14;s++){
            int ih = s/7, tap = s%7;
            #pragma unroll
            for (int j=0;j<8;j++)
                afr[s][j] = (short)f2b(w[(size_t)(o*64 + ih*32 + kq*8 + j)*7 + tap]);
        }
        floatx4 acc[7];
        #pragma unroll
        for (int i=0;i<7;i++) acc[i] = (floatx4){0.f,0.f,0.f,0.f};
        #pragma unroll
        for (int sub=0; sub<7; sub++){
            #pragma unroll
            for (int s=0;s<14;s++){
                int ih = s/7, tap = s%7;
                short8 bfr = *reinterpret_cast<const short8*>(
                                &xs[(sub*16 + m + tap)*72 + ih*32 + kq*8]);
                acc[sub] = __builtin_amdgcn_mfma_f32_16x16x32_bf16(afr[s], bfr, acc[sub], 0,0,0);
            }
        }
        int ob = ot*16 + kq*4;
        float bv[4];
        #pragma unroll
        for (int r=0;r<4;r++) bv[r] = bias[ob + r];
        #pragma unroll
        for (int sub=0; sub<7; sub++){
            #pragma unroll
            for (int r=0;r<4;r++){
                float v = lk(acc[sub][r] + bv[r]);
                v = fmaxf(v, __shfl_xor(v, 1));
                v = fmaxf(v, __shfl_xor(v, 2));
                int pp = (sub*16 + n) >> 2;
                if (wrm && pp < 25)
                    p2[(size_t)(b*128 + ob + r)*125 + tile*25 + pp] = v;
            }
        }
    }
}

// ---------------------------------------------------------------------------
// Sliding column sums (unchanged)
// ---------------------------------------------------------------------------
__global__ __launch_bounds__(256) void k_colsum(const float* __restrict__ p2,
        float* __restrict__ ssum)
{
    int g = blockIdx.x*256 + threadIdx.x;
    int ic = g & 127, b = g >> 7;
    const float* pp = p2 + ((size_t)(b*128+ic))*125;
    float c = 0.f;
    for (int t=0;t<119;t++) c += pp[t];
    float* op = ssum + (size_t)(b*128+ic)*7;
    op[0] = c;
    #pragma unroll
    for (int s=0;s<6;s++){ c = c - pp[s] + pp[s+119]; op[s+1] = c; }
}

__global__ __launch_bounds__(128) void k_feat(const float* __restrict__ ssum,
        const float* __restrict__ w, const float* __restrict__ bias,
        float* __restrict__ feat)
{
    __shared__ float ss[896];
    int b = blockIdx.x, o = threadIdx.x;
    for (int j=threadIdx.x; j<896; j+=128) ss[j] = ssum[(size_t)b*896 + j];
    __syncthreads();
    const float* wp = w + o*896;
    float s = 0.f;
    for (int j=0;j<896;j++) s += wp[j]*ss[j];
    feat[b*128+o] = s*(1.f/119.f) + bias[o];
}

__global__ __launch_bounds__(64) void k_cls(const float* __restrict__ feat,
        const float* __restrict__ cw, const float* __restrict__ cb,
        float* __restrict__ out)
{
    __shared__ float lg[5];
    int b = blockIdx.x;
    if (threadIdx.x < 5){
        const float* fp = feat + b*128;
        const float* wp = cw + threadIdx.x*128;
        float s = 0.f;
        for (int o=0;o<128;o++) s += fp[o]*wp[o];
        lg[threadIdx.x] = s + cb[threadIdx.x];
    }
    __syncthreads();
    if (threadIdx.x == 0){
        float mx = -3.4e38f;
        for (int c=0;c<5;c++) mx = fmaxf(mx, lg[c]);
        float se = 0.f;
        for (int c=0;c<5;c++) se += expf(lg[c]-mx);
        float lse = mx + logf(se);
        for (int c=0;c<5;c++) out[b*5+c] = lg[c]-lse;
    }
}

extern "C" void kernel_launch(void* const* d_in, const int* in_sizes, int n_in,
                              void* d_out, int out_size, void* d_ws, size_t ws_size,
                              hipStream_t stream)
{
    const float* x   = (const float*)d_in[0];
    const float* hw1 = (const float*)d_in[2];
    const float* hb1 = (const float*)d_in[3];
    const float* hw2 = (const float*)d_in[4];
    const float* hb2 = (const float*)d_in[5];
    const float* hw3 = (const float*)d_in[6];
    const float* hb3 = (const float*)d_in[7];
    const float* hl1 = (const float*)d_in[8];
    const float* hl2 = (const float*)d_in[9];
    const float* gw  = (const float*)d_in[10];
    const float* gb0 = (const float*)d_in[11];
    const float* ew2 = (const float*)d_in[12];
    const float* eb2 = (const float*)d_in[13];
    const float* ew3 = (const float*)d_in[14];
    const float* eb3 = (const float*)d_in[15];
    const float* cw  = (const float*)d_in[16];
    const float* cb  = (const float*)d_in[17];
    float* out = (float*)d_out;

    // workspace (float offsets), peak 66 MB < 91.2 MB proven available:
    //   latent @0 (786,432) | partial @786,432 (3,145,728) | h2 @3,932,160
    //   (6,291,456 f32) | h1 bf16 @10,223,616 (occupies 6,291,456 f)
    //   tail overlays: t1 @786,432; idxb/n0f; zp bf16 @810,000 (2,080,768 f);
    //   p2 @5,000,000; ssum @7,100,000; feat @7,300,000
    float* f       = (float*)d_ws;
    float* latent  = f;
    float* partial = f + 786432;
    float* h2      = f + 3932160;
    u16*   h1b     = (u16*)(f + 10223616);
    float* t1      = f + 786432;
    int*   idxb    = (int*)(f + 806432);
    float* n0f     = f + 808432;
    u16*   zpb     = (u16*)(f + 810000);
    float* p2      = f + 5000000;
    float* ssum    = f + 7100000;
    float* feat    = f + 7300000;

    k_hconv1<<<3072, 256, 0, stream>>>(x, hw1, hb1, h1b);
    k_hconv2<<<1024, 256, 0, stream>>>(h1b, hw2, hb2, h2);
    k_hconv3a<<<1536, 256, 0, stream>>>(h2, hw3, partial);
    k_hconv3b<<<3072, 256, 0, stream>>>(partial, hb3, latent);
    k_lin1<<<128, 256, 0, stream>>>(latent, hl1, t1);
    k_topk<<<128, 128, 0, stream>>>(t1, hl2, idxb, n0f);
    k_gconv<<<512, 256, 0, stream>>>(x, idxb, n0f, gw, gb0, zpb);
    k_econv2<<<640, 256, 0, stream>>>(zpb, ew2, eb2, p2);
    k_colsum<<<64, 256, 0, stream>>>(p2, ssum);
    k_feat<<<128, 128, 0, stream>>>(ssum, ew3, eb3, feat);
    k_cls<<<128, 64, 0, stream>>>(feat, cw, cb, out);
}

// Round 6
// 585.964 us; speedup vs baseline: 3.2414x; 1.4032x over previous
//
#include <hip/hip_runtime.h>
#include <hip/hip_bf16.h>
#include <math.h>

typedef unsigned short u16;
typedef __attribute__((ext_vector_type(8))) short short8;
typedef __attribute__((ext_vector_type(4))) float floatx4;

__device__ __forceinline__ float lk(float v){ return v >= 0.f ? v : 0.01f*v; }
__device__ __forceinline__ u16 f2b(float f){
    __hip_bfloat16 h = __float2bfloat16(f);
    return *reinterpret_cast<u16*>(&h);
}
__device__ __forceinline__ float b2f(u16 u){
    union { unsigned u; float f; } c; c.u = ((unsigned)u) << 16; return c.f;
}

// ---------------------------------------------------------------------------
// Hypernet conv1 (MFMA bf16): x[128,16,12288] f32, w[32,16,7], reflect-same,
// leaky, meanpool4 -> h1 bf16 [128,32,3072].   (unchanged from round 5)
// ---------------------------------------------------------------------------
__global__ __launch_bounds__(256) void k_hconv1(const float* __restrict__ x,
        const float* __restrict__ w, const float* __restrict__ bias,
        u16* __restrict__ h1)
{
    __shared__ __align__(16) u16 xs[520*24];
    int b = blockIdx.x / 24, tile = blockIdx.x % 24;
    int g0 = tile*512;
    int tid = threadIdx.x;
    const float* xb = x + (size_t)b*16*12288;
    for (int row = tid; row < 520; row += 256){
        int t = g0 + row - 3;
        t = t < 0 ? -t : (t >= 12288 ? 2*12288-2-t : t);
        u16 v[16];
        #pragma unroll
        for (int ic=0;ic<16;ic++) v[ic] = f2b(xb[(size_t)ic*12288 + t]);
        short8 p0, p1;
        #pragma unroll
        for (int j=0;j<8;j++){ p0[j] = (short)v[j]; p1[j] = (short)v[8+j]; }
        *reinterpret_cast<short8*>(&xs[row*24])     = p0;
        *reinterpret_cast<short8*>(&xs[row*24 + 8]) = p1;
    }
    __syncthreads();
    int wv = tid >> 6, lane = tid & 63;
    int m = lane & 15, kq = lane >> 4;
    int ohalf = wv & 1, thalf = wv >> 1;
    int o = ohalf*16 + m;
    short8 afr[4];
    #pragma unroll
    for (int s=0;s<4;s++){
        int tap = 2*s + (kq>>1);
        #pragma unroll
        for (int j=0;j<8;j++){
            int ic = (kq&1)*8 + j;
            afr[s][j] = (tap < 7) ? (short)f2b(w[(o*16+ic)*7 + tap]) : (short)0;
        }
    }
    floatx4 acc[16];
    #pragma unroll
    for (int i=0;i<16;i++) acc[i] = (floatx4){0.f,0.f,0.f,0.f};
    int tb0 = thalf*256;
    #pragma unroll
    for (int sub=0; sub<16; sub++){
        int tb = tb0 + sub*16;
        #pragma unroll
        for (int s=0;s<4;s++){
            int tap = 2*s + (kq>>1);
            short8 bfr = *reinterpret_cast<const short8*>(
                            &xs[(tb + m + tap)*24 + (kq&1)*8]);
            acc[sub] = __builtin_amdgcn_mfma_f32_16x16x32_bf16(afr[s], bfr, acc[sub], 0,0,0);
        }
    }
    int ob = ohalf*16 + kq*4;
    float bv[4];
    #pragma unroll
    for (int r=0;r<4;r++) bv[r] = bias[ob + r];
    int n = lane & 15;
    bool wr = (lane & 3) == 0;
    #pragma unroll
    for (int sub=0; sub<16; sub++){
        int tg = g0 + tb0 + sub*16 + n;
        #pragma unroll
        for (int r=0;r<4;r++){
            float v = lk(acc[sub][r] + bv[r]);
            v += __shfl_xor(v, 1);
            v += __shfl_xor(v, 2);
            if (wr) h1[(size_t)(b*32 + ob + r)*3072 + (tg>>2)] = f2b(v*0.25f);
        }
    }
}

// ---------------------------------------------------------------------------
// Hypernet conv2 (MFMA bf16): h1 bf16 -> h2 f32 [128,64,768]. (unchanged)
// ---------------------------------------------------------------------------
__global__ __launch_bounds__(256,1) void k_hconv2(const u16* __restrict__ h1,
        const float* __restrict__ w, const float* __restrict__ bias,
        float* __restrict__ h2)
{
    __shared__ __align__(16) u16 xs[390*40];
    int b = blockIdx.x >> 3, tile = blockIdx.x & 7;
    int g0 = tile*384;
    int tid = threadIdx.x;
    for (int row = tid; row < 390; row += 256){
        int t = g0 + row - 3;
        t = t < 0 ? -t : (t >= 3072 ? 2*3072-2-t : t);
        u16 v[32];
        #pragma unroll
        for (int ic=0;ic<32;ic++) v[ic] = h1[(size_t)(b*32+ic)*3072 + t];
        #pragma unroll
        for (int q=0;q<4;q++){
            short8 p;
            #pragma unroll
            for (int j=0;j<8;j++) p[j] = (short)v[q*8+j];
            *reinterpret_cast<short8*>(&xs[row*40 + q*8]) = p;
        }
    }
    __syncthreads();
    int wv = tid >> 6, lane = tid & 63;
    int m = lane & 15, kq = lane >> 4;
    int o = wv*16 + m;
    short8 afr[7];
    #pragma unroll
    for (int s=0;s<7;s++){
        #pragma unroll
        for (int j=0;j<8;j++)
            afr[s][j] = (short)f2b(w[(size_t)(o*32 + kq*8 + j)*7 + s]);
    }
    floatx4 acc[24];
    #pragma unroll
    for (int i=0;i<24;i++) acc[i] = (floatx4){0.f,0.f,0.f,0.f};
    for (int sub=0; sub<24; sub++){
        int tb = sub*16;
        #pragma unroll
        for (int s=0;s<7;s++){
            short8 bfr = *reinterpret_cast<const short8*>(
                            &xs[(tb + m + s)*40 + kq*8]);
            acc[sub] = __builtin_amdgcn_mfma_f32_16x16x32_bf16(afr[s], bfr, acc[sub], 0,0,0);
        }
    }
    int ob = wv*16 + kq*4;
    float bv[4];
    #pragma unroll
    for (int r=0;r<4;r++) bv[r] = bias[ob + r];
    int n = lane & 15;
    bool wr = (lane & 3) == 0;
    #pragma unroll
    for (int sub=0; sub<24; sub++){
        int tg = g0 + sub*16 + n;
        #pragma unroll
        for (int r=0;r<4;r++){
            float v = lk(acc[sub][r] + bv[r]);
            v += __shfl_xor(v, 1);
            v += __shfl_xor(v, 2);
            if (wr) h2[(size_t)(b*64 + ob + r)*768 + (tg>>2)] = v*0.25f;
        }
    }
}

// ---------------------------------------------------------------------------
// Hypernet conv3 stage A: ic-split partials; position runs of 4 (2x grid of
// round 5 for latency hiding). 786432 threads = 192 ug x 8 c x 128 b x 4 icq.
// ---------------------------------------------------------------------------
__global__ __launch_bounds__(256) void k_hconv3a(const float* __restrict__ in,
        const float* __restrict__ w, float* __restrict__ partial)
{
    int g = blockIdx.x*256 + threadIdx.x;
    int ug = g % 192; int r = g / 192;
    int c = r & 7; int b = (r >> 3) & 127; int icq = r >> 10;
    int t0 = ug*4 - 3;
    int tt[10];
    #pragma unroll
    for (int j=0;j<10;j++){ int t=t0+j; tt[j] = t<0 ? -t : (t>=768 ? 2*768-2-t : t); }
    float acc[4];
    #pragma unroll
    for (int i=0;i<4;i++) acc[i]=0.f;
    for (int ic=icq*16; ic<icq*16+16; ic++){
        const float* xc = in + ((size_t)(b*64+ic))*768;
        float xr[10];
        #pragma unroll
        for (int j=0;j<10;j++) xr[j] = xc[tt[j]];
        const float* wp = w + (c*64+ic)*7;
        float wr[7];
        #pragma unroll
        for (int s=0;s<7;s++) wr[s] = wp[s];
        #pragma unroll
        for (int s=0;s<7;s++)
            #pragma unroll
            for (int l=0;l<4;l++) acc[l] += wr[s]*xr[l+s];
    }
    float* op = partial + ((size_t)(icq*1024 + b*8 + c))*768 + ug*4;
    #pragma unroll
    for (int l=0;l<4;l++) op[l] = acc[l];
}

__global__ __launch_bounds__(256) void k_hconv3b(const float* __restrict__ partial,
        const float* __restrict__ bias, float* __restrict__ latent)
{
    int idx = blockIdx.x*256 + threadIdx.x;
    int pos = idx % 768; int r = idx / 768;
    int c = r & 7; int b = r >> 3;
    float s = bias[c];
    #pragma unroll
    for (int q=0;q<4;q++) s += partial[((size_t)(q*1024 + b*8 + c))*768 + pos];
    latent[(size_t)b*6144 + c*768 + pos] = tanhf(s);
}

// ---------------------------------------------------------------------------
// t1 = leaky(latent @ hl1^T).  Grid = 128 b x 6 n-tiles = 768 blocks.
// Latent staged in LDS once; wave computes 4 n's, lane-strided float4 dots.
// No large register arrays (round-5 spill fix).
// ---------------------------------------------------------------------------
__global__ __launch_bounds__(256) void k_lin1(const float* __restrict__ latent,
        const float* __restrict__ hl1, float* __restrict__ t1)
{
    __shared__ float ls[6144];
    int b = blockIdx.x / 6, ntile = blockIdx.x % 6;
    int tid = threadIdx.x;
    const float4* lp = reinterpret_cast<const float4*>(latent + (size_t)b*6144);
    float4* lsv = reinterpret_cast<float4*>(ls);
    for (int i = tid; i < 1536; i += 256) lsv[i] = lp[i];
    __syncthreads();
    int wv = tid >> 6, lane = tid & 63;
    #pragma unroll
    for (int nn=0; nn<4; nn++){
        int n = ntile*16 + wv*4 + nn;
        const float4* wp = reinterpret_cast<const float4*>(hl1 + (size_t)n*6144);
        float s = 0.f;
        #pragma unroll
        for (int j=0;j<24;j++){
            float4 q = wp[lane + 64*j];
            float4 l4 = lsv[lane + 64*j];
            s += l4.x*q.x + l4.y*q.y + l4.z*q.z + l4.w*q.w;
        }
        #pragma unroll
        for (int off=32; off; off>>=1) s += __shfl_down(s, off);
        if (lane==0) t1[b*96+n] = lk(s);
    }
}

// ---------------------------------------------------------------------------
// logits = t1 @ hl2^T; top-5; n0 = #(idx<6)   (unchanged)
// ---------------------------------------------------------------------------
__global__ __launch_bounds__(128) void k_topk(const float* __restrict__ t1,
        const float* __restrict__ hl2, int* __restrict__ idxb, float* __restrict__ n0f)
{
    __shared__ float lg[96];
    int b = blockIdx.x, n = threadIdx.x;
    if (n < 96){
        float s = 0.f;
        const float* tp = t1 + b*96;
        const float* wp = hl2 + n*96;
        for (int m=0;m<96;m++) s += tp[m]*wp[m];
        lg[n] = s;
    }
    __syncthreads();
    if (threadIdx.x == 0){
        unsigned long long u0=0ull, u1=0ull;
        float n0 = 0.f;
        for (int k=0;k<5;k++){
            float best = -3.4e38f; int bi = 0;
            for (int m=0;m<96;m++){
                bool used = m<64 ? ((u0>>m)&1ull) : ((u1>>(m-64))&1ull);
                if (!used && lg[m] > best){ best = lg[m]; bi = m; }
            }
            if (bi<64) u0 |= 1ull<<bi; else u1 |= 1ull<<(bi-64);
            idxb[b*5+k] = bi;
            if (bi < 6) n0 += 1.f;
        }
        n0f[b] = n0;
    }
}

// ---------------------------------------------------------------------------
// Grouped idx conv ks=15 + bias + leaky + maxpool4 -> zp bf16 (unchanged)
// ---------------------------------------------------------------------------
__global__ __launch_bounds__(256) void k_gconv(const float* __restrict__ x,
        const int* __restrict__ idxb, const float* __restrict__ n0f,
        const float* __restrict__ gw, const float* __restrict__ gb0,
        u16* __restrict__ zp)
{
    __shared__ float xs[5][522];
    int b = blockIdx.x >> 2, qc = blockIdx.x & 3;
    int tid = threadIdx.x;
    int l0 = qc*508;
    for (int j=tid; j<5*522; j+=256){
        int k = j/522, u = j - k*522;
        int n = idxb[b*5+k];
        xs[k][u] = x[(size_t)b*196608 + n*2048 + l0 + u];
    }
    __syncthreads();
    int o = tid >> 2, qs = tid & 3;
    float wreg[5][15];
    #pragma unroll
    for (int k=0;k<5;k++){
        int n = idxb[b*5+k]; int gi = n/6;
        const float* wp = gw + gi*960 + o*15;
        #pragma unroll
        for (int s=0;s<15;s++) wreg[k][s] = wp[s];
    }
    float bv = n0f[b]*gb0[o];
    for (int q=qs; q<127; q+=4){
        int lb = 4*q;
        float s0=bv, s1=bv, s2=bv, s3=bv;
        #pragma unroll
        for (int k=0;k<5;k++){
            float xw[18];
            #pragma unroll
            for (int j=0;j<18;j++) xw[j] = xs[k][lb+j];
            #pragma unroll
            for (int sp=0;sp<15;sp++){
                s0 += wreg[k][sp]*xw[sp];
                s1 += wreg[k][sp]*xw[sp+1];
                s2 += wreg[k][sp]*xw[sp+2];
                s3 += wreg[k][sp]*xw[sp+3];
            }
        }
        float mx = fmaxf(fmaxf(lk(s0),lk(s1)), fmaxf(lk(s2),lk(s3)));
        zp[((size_t)(b*64+o))*508 + qc*127 + q] = f2b(mx);
    }
}

// ---------------------------------------------------------------------------
// Encoder conv2 (MFMA bf16) -> p2 f32 [128,128,125]   (unchanged)
// ---------------------------------------------------------------------------
__global__ __launch_bounds__(256,1) void k_econv2(const u16* __restrict__ zp,
        const float* __restrict__ w, const float* __restrict__ bias,
        float* __restrict__ p2)
{
    __shared__ __align__(16) u16 xs[118*72];
    int b = blockIdx.x / 5, tile = blockIdx.x % 5;
    int tid = threadIdx.x;
    if (tid < 118){
        int t = tile*100 + tid; if (t > 507) t = 507;
        u16 v[64];
        #pragma unroll
        for (int ic=0;ic<64;ic++) v[ic] = zp[(size_t)(b*64+ic)*508 + t];
        #pragma unroll
        for (int q=0;q<8;q++){
            short8 p;
            #pragma unroll
            for (int j=0;j<8;j++) p[j] = (short)v[q*8+j];
            *reinterpret_cast<short8*>(&xs[tid*72 + q*8]) = p;
        }
    }
    __syncthreads();
    int wv = tid >> 6, lane = tid & 63;
    int m = lane & 15, kq = lane >> 4;
    int n = lane & 15;
    bool wrm = (lane & 3) == 0;
    for (int half=0; half<2; half++){
        int ot = wv + 4*half;
        int o = ot*16 + m;
        short8 afr[14];
        #pragma unroll
        for (int s=0;s<14;s++){
            int ih = s/7, tap = s%7;
            #pragma unroll
            for (int j=0;j<8;j++)
                afr[s][j] = (short)f2b(w[(size_t)(o*64 + ih*32 + kq*8 + j)*7 + tap]);
        }
        floatx4 acc[7];
        #pragma unroll
        for (int i=0;i<7;i++) acc[i] = (floatx4){0.f,0.f,0.f,0.f};
        #pragma unroll
        for (int sub=0; sub<7; sub++){
            #pragma unroll
            for (int s=0;s<14;s++){
                int ih = s/7, tap = s%7;
                short8 bfr = *reinterpret_cast<const short8*>(
                                &xs[(sub*16 + m + tap)*72 + ih*32 + kq*8]);
                acc[sub] = __builtin_amdgcn_mfma_f32_16x16x32_bf16(afr[s], bfr, acc[sub], 0,0,0);
            }
        }
        int ob = ot*16 + kq*4;
        float bv[4];
        #pragma unroll
        for (int r=0;r<4;r++) bv[r] = bias[ob + r];
        #pragma unroll
        for (int sub=0; sub<7; sub++){
            #pragma unroll
            for (int r=0;r<4;r++){
                float v = lk(acc[sub][r] + bv[r]);
                v = fmaxf(v, __shfl_xor(v, 1));
                v = fmaxf(v, __shfl_xor(v, 2));
                int pp = (sub*16 + n) >> 2;
                if (wrm && pp < 25)
                    p2[(size_t)(b*128 + ob + r)*125 + tile*25 + pp] = v;
            }
        }
    }
}

// ---------------------------------------------------------------------------
// Sliding column sums (unchanged)
// ---------------------------------------------------------------------------
__global__ __launch_bounds__(256) void k_colsum(const float* __restrict__ p2,
        float* __restrict__ ssum)
{
    int g = blockIdx.x*256 + threadIdx.x;
    int ic = g & 127, b = g >> 7;
    const float* pp = p2 + ((size_t)(b*128+ic))*125;
    float c = 0.f;
    for (int t=0;t<119;t++) c += pp[t];
    float* op = ssum + (size_t)(b*128+ic)*7;
    op[0] = c;
    #pragma unroll
    for (int s=0;s<6;s++){ c = c - pp[s] + pp[s+119]; op[s+1] = c; }
}

__global__ __launch_bounds__(128) void k_feat(const float* __restrict__ ssum,
        const float* __restrict__ w, const float* __restrict__ bias,
        float* __restrict__ feat)
{
    __shared__ float ss[896];
    int b = blockIdx.x, o = threadIdx.x;
    for (int j=threadIdx.x; j<896; j+=128) ss[j] = ssum[(size_t)b*896 + j];
    __syncthreads();
    const float* wp = w + o*896;
    float s = 0.f;
    for (int j=0;j<896;j++) s += wp[j]*ss[j];
    feat[b*128+o] = s*(1.f/119.f) + bias[o];
}

__global__ __launch_bounds__(64) void k_cls(const float* __restrict__ feat,
        const float* __restrict__ cw, const float* __restrict__ cb,
        float* __restrict__ out)
{
    __shared__ float lg[5];
    int b = blockIdx.x;
    if (threadIdx.x < 5){
        const float* fp = feat + b*128;
        const float* wp = cw + threadIdx.x*128;
        float s = 0.f;
        for (int o=0;o<128;o++) s += fp[o]*wp[o];
        lg[threadIdx.x] = s + cb[threadIdx.x];
    }
    __syncthreads();
    if (threadIdx.x == 0){
        float mx = -3.4e38f;
        for (int c=0;c<5;c++) mx = fmaxf(mx, lg[c]);
        float se = 0.f;
        for (int c=0;c<5;c++) se += expf(lg[c]-mx);
        float lse = mx + logf(se);
        for (int c=0;c<5;c++) out[b*5+c] = lg[c]-lse;
    }
}

extern "C" void kernel_launch(void* const* d_in, const int* in_sizes, int n_in,
                              void* d_out, int out_size, void* d_ws, size_t ws_size,
                              hipStream_t stream)
{
    const float* x   = (const float*)d_in[0];
    const float* hw1 = (const float*)d_in[2];
    const float* hb1 = (const float*)d_in[3];
    const float* hw2 = (const float*)d_in[4];
    const float* hb2 = (const float*)d_in[5];
    const float* hw3 = (const float*)d_in[6];
    const float* hb3 = (const float*)d_in[7];
    const float* hl1 = (const float*)d_in[8];
    const float* hl2 = (const float*)d_in[9];
    const float* gw  = (const float*)d_in[10];
    const float* gb0 = (const float*)d_in[11];
    const float* ew2 = (const float*)d_in[12];
    const float* eb2 = (const float*)d_in[13];
    const float* ew3 = (const float*)d_in[14];
    const float* eb3 = (const float*)d_in[15];
    const float* cw  = (const float*)d_in[16];
    const float* cb  = (const float*)d_in[17];
    float* out = (float*)d_out;

    float* f       = (float*)d_ws;
    float* latent  = f;
    float* partial = f + 786432;
    float* h2      = f + 3932160;
    u16*   h1b     = (u16*)(f + 10223616);
    float* t1      = f + 786432;
    int*   idxb    = (int*)(f + 806432);
    float* n0f     = f + 808432;
    u16*   zpb     = (u16*)(f + 810000);
    float* p2      = f + 5000000;
    float* ssum    = f + 7100000;
    float* feat    = f + 7300000;

    k_hconv1<<<3072, 256, 0, stream>>>(x, hw1, hb1, h1b);
    k_hconv2<<<1024, 256, 0, stream>>>(h1b, hw2, hb2, h2);
    k_hconv3a<<<3072, 256, 0, stream>>>(h2, hw3, partial);
    k_hconv3b<<<3072, 256, 0, stream>>>(partial, hb3, latent);
    k_lin1<<<768, 256, 0, stream>>>(latent, hl1, t1);
    k_topk<<<128, 128, 0, stream>>>(t1, hl2, idxb, n0f);
    k_gconv<<<512, 256, 0, stream>>>(x, idxb, n0f, gw, gb0, zpb);
    k_econv2<<<640, 256, 0, stream>>>(zpb, ew2, eb2, p2);
    k_colsum<<<64, 256, 0, stream>>>(p2, ssum);
    k_feat<<<128, 128, 0, stream>>>(ssum, ew3, eb3, feat);
    k_cls<<<128, 64, 0, stream>>>(feat, cw, cb, out);
}

// Round 7
// 491.854 us; speedup vs baseline: 3.8616x; 1.1913x over previous
//
#include <hip/hip_runtime.h>
#include <hip/hip_bf16.h>
#include <math.h>

typedef unsigned short u16;
typedef __attribute__((ext_vector_type(8))) short short8;
typedef __attribute__((ext_vector_type(4))) float floatx4;

__device__ __forceinline__ float lk(float v){ return v >= 0.f ? v : 0.01f*v; }
__device__ __forceinline__ u16 f2b(float f){
    __hip_bfloat16 h = __float2bfloat16(f);
    return *reinterpret_cast<u16*>(&h);
}

// ---------------------------------------------------------------------------
// Hypernet conv1 (MFMA bf16): x[128,16,12288] f32 -> h1 bf16 [128,32,3072].
// (unchanged from round 5)
// ---------------------------------------------------------------------------
__global__ __launch_bounds__(256) void k_hconv1(const float* __restrict__ x,
        const float* __restrict__ w, const float* __restrict__ bias,
        u16* __restrict__ h1)
{
    __shared__ __align__(16) u16 xs[520*24];
    int b = blockIdx.x / 24, tile = blockIdx.x % 24;
    int g0 = tile*512;
    int tid = threadIdx.x;
    const float* xb = x + (size_t)b*16*12288;
    for (int row = tid; row < 520; row += 256){
        int t = g0 + row - 3;
        t = t < 0 ? -t : (t >= 12288 ? 2*12288-2-t : t);
        u16 v[16];
        #pragma unroll
        for (int ic=0;ic<16;ic++) v[ic] = f2b(xb[(size_t)ic*12288 + t]);
        short8 p0, p1;
        #pragma unroll
        for (int j=0;j<8;j++){ p0[j] = (short)v[j]; p1[j] = (short)v[8+j]; }
        *reinterpret_cast<short8*>(&xs[row*24])     = p0;
        *reinterpret_cast<short8*>(&xs[row*24 + 8]) = p1;
    }
    __syncthreads();
    int wv = tid >> 6, lane = tid & 63;
    int m = lane & 15, kq = lane >> 4;
    int ohalf = wv & 1, thalf = wv >> 1;
    int o = ohalf*16 + m;
    short8 afr[4];
    #pragma unroll
    for (int s=0;s<4;s++){
        int tap = 2*s + (kq>>1);
        #pragma unroll
        for (int j=0;j<8;j++){
            int ic = (kq&1)*8 + j;
            afr[s][j] = (tap < 7) ? (short)f2b(w[(o*16+ic)*7 + tap]) : (short)0;
        }
    }
    floatx4 acc[16];
    #pragma unroll
    for (int i=0;i<16;i++) acc[i] = (floatx4){0.f,0.f,0.f,0.f};
    int tb0 = thalf*256;
    #pragma unroll
    for (int sub=0; sub<16; sub++){
        int tb = tb0 + sub*16;
        #pragma unroll
        for (int s=0;s<4;s++){
            int tap = 2*s + (kq>>1);
            short8 bfr = *reinterpret_cast<const short8*>(
                            &xs[(tb + m + tap)*24 + (kq&1)*8]);
            acc[sub] = __builtin_amdgcn_mfma_f32_16x16x32_bf16(afr[s], bfr, acc[sub], 0,0,0);
        }
    }
    int ob = ohalf*16 + kq*4;
    float bv[4];
    #pragma unroll
    for (int r=0;r<4;r++) bv[r] = bias[ob + r];
    int n = lane & 15;
    bool wr = (lane & 3) == 0;
    #pragma unroll
    for (int sub=0; sub<16; sub++){
        int tg = g0 + tb0 + sub*16 + n;
        #pragma unroll
        for (int r=0;r<4;r++){
            float v = lk(acc[sub][r] + bv[r]);
            v += __shfl_xor(v, 1);
            v += __shfl_xor(v, 2);
            if (wr) h1[(size_t)(b*32 + ob + r)*3072 + (tg>>2)] = f2b(v*0.25f);
        }
    }
}

// ---------------------------------------------------------------------------
// Hypernet conv2 (MFMA bf16): h1 bf16 -> h2 f32 [128,64,768]. (unchanged)
// ---------------------------------------------------------------------------
__global__ __launch_bounds__(256,1) void k_hconv2(const u16* __restrict__ h1,
        const float* __restrict__ w, const float* __restrict__ bias,
        float* __restrict__ h2)
{
    __shared__ __align__(16) u16 xs[390*40];
    int b = blockIdx.x >> 3, tile = blockIdx.x & 7;
    int g0 = tile*384;
    int tid = threadIdx.x;
    for (int row = tid; row < 390; row += 256){
        int t = g0 + row - 3;
        t = t < 0 ? -t : (t >= 3072 ? 2*3072-2-t : t);
        u16 v[32];
        #pragma unroll
        for (int ic=0;ic<32;ic++) v[ic] = h1[(size_t)(b*32+ic)*3072 + t];
        #pragma unroll
        for (int q=0;q<4;q++){
            short8 p;
            #pragma unroll
            for (int j=0;j<8;j++) p[j] = (short)v[q*8+j];
            *reinterpret_cast<short8*>(&xs[row*40 + q*8]) = p;
        }
    }
    __syncthreads();
    int wv = tid >> 6, lane = tid & 63;
    int m = lane & 15, kq = lane >> 4;
    int o = wv*16 + m;
    short8 afr[7];
    #pragma unroll
    for (int s=0;s<7;s++){
        #pragma unroll
        for (int j=0;j<8;j++)
            afr[s][j] = (short)f2b(w[(size_t)(o*32 + kq*8 + j)*7 + s]);
    }
    floatx4 acc[24];
    #pragma unroll
    for (int i=0;i<24;i++) acc[i] = (floatx4){0.f,0.f,0.f,0.f};
    for (int sub=0; sub<24; sub++){
        int tb = sub*16;
        #pragma unroll
        for (int s=0;s<7;s++){
            short8 bfr = *reinterpret_cast<const short8*>(
                            &xs[(tb + m + s)*40 + kq*8]);
            acc[sub] = __builtin_amdgcn_mfma_f32_16x16x32_bf16(afr[s], bfr, acc[sub], 0,0,0);
        }
    }
    int ob = wv*16 + kq*4;
    float bv[4];
    #pragma unroll
    for (int r=0;r<4;r++) bv[r] = bias[ob + r];
    int n = lane & 15;
    bool wr = (lane & 3) == 0;
    #pragma unroll
    for (int sub=0; sub<24; sub++){
        int tg = g0 + sub*16 + n;
        #pragma unroll
        for (int r=0;r<4;r++){
            float v = lk(acc[sub][r] + bv[r]);
            v += __shfl_xor(v, 1);
            v += __shfl_xor(v, 2);
            if (wr) h2[(size_t)(b*64 + ob + r)*768 + (tg>>2)] = v*0.25f;
        }
    }
}

// ---------------------------------------------------------------------------
// Hypernet conv3 FUSED (round-6 fix): h2 f32 [128,64,768], w[8,64,7],
// reflect-same, + bias + tanh -> latent[128,6144].
// Block = (b, tile of 192 pos); grid 512.  LDS: 64 ic x 198 (stride 200)
// = 51.2 KB -> 3 blocks/CU.  256 thr = 8 c x 32 runs-of-6.
// Each h2 element fetched from HBM exactly once (vs ~3x + 8x L2 before).
// Lanes: 2 c (address-broadcast) x 32 runs stride-6 -> <=2-way LDS aliasing.
// ---------------------------------------------------------------------------
__global__ __launch_bounds__(256) void k_hconv3(const float* __restrict__ h2,
        const float* __restrict__ w, const float* __restrict__ bias,
        float* __restrict__ latent)
{
    __shared__ float xs[64*200];
    int b = blockIdx.x >> 2, tile = blockIdx.x & 3;
    int g0 = tile*192;
    int tid = threadIdx.x;
    const float* hb = h2 + (size_t)b*64*768;
    for (int idx = tid; idx < 64*198; idx += 256){
        int ic = idx / 198, jj = idx - ic*198;
        int t = g0 + jj - 3;
        t = t < 0 ? -t : (t >= 768 ? 2*768-2-t : t);
        xs[ic*200 + jj] = hb[(size_t)ic*768 + t];
    }
    __syncthreads();
    int c = tid >> 5, run = tid & 31;
    int p0 = run*6;
    float acc[6];
    #pragma unroll
    for (int l=0;l<6;l++) acc[l] = 0.f;
    for (int ic=0; ic<64; ic++){
        const float* wp = w + (c*64+ic)*7;
        float wr[7];
        #pragma unroll
        for (int s=0;s<7;s++) wr[s] = wp[s];
        const float* xr = xs + ic*200 + p0;
        float xw[12];
        #pragma unroll
        for (int j=0;j<12;j++) xw[j] = xr[j];
        #pragma unroll
        for (int s=0;s<7;s++)
            #pragma unroll
            for (int l=0;l<6;l++) acc[l] += wr[s]*xw[l+s];
    }
    float bv = bias[c];
    float* op = latent + (size_t)b*6144 + c*768 + g0 + p0;
    #pragma unroll
    for (int l=0;l<6;l++) op[l] = tanhf(acc[l] + bv);
}

// ---------------------------------------------------------------------------
// t1 = leaky(latent @ hl1^T).  Grid = 128 b x 6 n-tiles. (unchanged)
// ---------------------------------------------------------------------------
__global__ __launch_bounds__(256) void k_lin1(const float* __restrict__ latent,
        const float* __restrict__ hl1, float* __restrict__ t1)
{
    __shared__ float ls[6144];
    int b = blockIdx.x / 6, ntile = blockIdx.x % 6;
    int tid = threadIdx.x;
    const float4* lp = reinterpret_cast<const float4*>(latent + (size_t)b*6144);
    float4* lsv = reinterpret_cast<float4*>(ls);
    for (int i = tid; i < 1536; i += 256) lsv[i] = lp[i];
    __syncthreads();
    int wv = tid >> 6, lane = tid & 63;
    #pragma unroll
    for (int nn=0; nn<4; nn++){
        int n = ntile*16 + wv*4 + nn;
        const float4* wp = reinterpret_cast<const float4*>(hl1 + (size_t)n*6144);
        float s = 0.f;
        #pragma unroll
        for (int j=0;j<24;j++){
            float4 q = wp[lane + 64*j];
            float4 l4 = lsv[lane + 64*j];
            s += l4.x*q.x + l4.y*q.y + l4.z*q.z + l4.w*q.w;
        }
        #pragma unroll
        for (int off=32; off; off>>=1) s += __shfl_down(s, off);
        if (lane==0) t1[b*96+n] = lk(s);
    }
}

// ---------------------------------------------------------------------------
// logits = t1 @ hl2^T; top-5; n0 = #(idx<6)   (unchanged)
// ---------------------------------------------------------------------------
__global__ __launch_bounds__(128) void k_topk(const float* __restrict__ t1,
        const float* __restrict__ hl2, int* __restrict__ idxb, float* __restrict__ n0f)
{
    __shared__ float lg[96];
    int b = blockIdx.x, n = threadIdx.x;
    if (n < 96){
        float s = 0.f;
        const float* tp = t1 + b*96;
        const float* wp = hl2 + n*96;
        for (int m=0;m<96;m++) s += tp[m]*wp[m];
        lg[n] = s;
    }
    __syncthreads();
    if (threadIdx.x == 0){
        unsigned long long u0=0ull, u1=0ull;
        float n0 = 0.f;
        for (int k=0;k<5;k++){
            float best = -3.4e38f; int bi = 0;
            for (int m=0;m<96;m++){
                bool used = m<64 ? ((u0>>m)&1ull) : ((u1>>(m-64))&1ull);
                if (!used && lg[m] > best){ best = lg[m]; bi = m; }
            }
            if (bi<64) u0 |= 1ull<<bi; else u1 |= 1ull<<(bi-64);
            idxb[b*5+k] = bi;
            if (bi < 6) n0 += 1.f;
        }
        n0f[b] = n0;
    }
}

// ---------------------------------------------------------------------------
// Grouped idx conv ks=15 + bias + leaky + maxpool4 -> zp bf16 (unchanged)
// ---------------------------------------------------------------------------
__global__ __launch_bounds__(256) void k_gconv(const float* __restrict__ x,
        const int* __restrict__ idxb, const float* __restrict__ n0f,
        const float* __restrict__ gw, const float* __restrict__ gb0,
        u16* __restrict__ zp)
{
    __shared__ float xs[5][522];
    int b = blockIdx.x >> 2, qc = blockIdx.x & 3;
    int tid = threadIdx.x;
    int l0 = qc*508;
    for (int j=tid; j<5*522; j+=256){
        int k = j/522, u = j - k*522;
        int n = idxb[b*5+k];
        xs[k][u] = x[(size_t)b*196608 + n*2048 + l0 + u];
    }
    __syncthreads();
    int o = tid >> 2, qs = tid & 3;
    float wreg[5][15];
    #pragma unroll
    for (int k=0;k<5;k++){
        int n = idxb[b*5+k]; int gi = n/6;
        const float* wp = gw + gi*960 + o*15;
        #pragma unroll
        for (int s=0;s<15;s++) wreg[k][s] = wp[s];
    }
    float bv = n0f[b]*gb0[o];
    for (int q=qs; q<127; q+=4){
        int lb = 4*q;
        float s0=bv, s1=bv, s2=bv, s3=bv;
        #pragma unroll
        for (int k=0;k<5;k++){
            float xw[18];
            #pragma unroll
            for (int j=0;j<18;j++) xw[j] = xs[k][lb+j];
            #pragma unroll
            for (int sp=0;sp<15;sp++){
                s0 += wreg[k][sp]*xw[sp];
                s1 += wreg[k][sp]*xw[sp+1];
                s2 += wreg[k][sp]*xw[sp+2];
                s3 += wreg[k][sp]*xw[sp+3];
            }
        }
        float mx = fmaxf(fmaxf(lk(s0),lk(s1)), fmaxf(lk(s2),lk(s3)));
        zp[((size_t)(b*64+o))*508 + qc*127 + q] = f2b(mx);
    }
}

// ---------------------------------------------------------------------------
// Encoder conv2 (MFMA bf16) -> p2 f32 [128,128,125]   (unchanged)
// ---------------------------------------------------------------------------
__global__ __launch_bounds__(256,1) void k_econv2(const u16* __restrict__ zp,
        const float* __restrict__ w, const float* __restrict__ bias,
        float* __restrict__ p2)
{
    __shared__ __align__(16) u16 xs[118*72];
    int b = blockIdx.x / 5, tile = blockIdx.x % 5;
    int tid = threadIdx.x;
    if (tid < 118){
        int t = tile*100 + tid; if (t > 507) t = 507;
        u16 v[64];
        #pragma unroll
        for (int ic=0;ic<64;ic++) v[ic] = zp[(size_t)(b*64+ic)*508 + t];
        #pragma unroll
        for (int q=0;q<8;q++){
            short8 p;
            #pragma unroll
            for (int j=0;j<8;j++) p[j] = (short)v[q*8+j];
            *reinterpret_cast<short8*>(&xs[tid*72 + q*8]) = p;
        }
    }
    __syncthreads();
    int wv = tid >> 6, lane = tid & 63;
    int m = lane & 15, kq = lane >> 4;
    int n = lane & 15;
    bool wrm = (lane & 3) == 0;
    for (int half=0; half<2; half++){
        int ot = wv + 4*half;
        int o = ot*16 + m;
        short8 afr[14];
        #pragma unroll
        for (int s=0;s<14;s++){
            int ih = s/7, tap = s%7;
            #pragma unroll
            for (int j=0;j<8;j++)
                afr[s][j] = (short)f2b(w[(size_t)(o*64 + ih*32 + kq*8 + j)*7 + tap]);
        }
        floatx4 acc[7];
        #pragma unroll
        for (int i=0;i<7;i++) acc[i] = (floatx4){0.f,0.f,0.f,0.f};
        #pragma unroll
        for (int sub=0; sub<7; sub++){
            #pragma unroll
            for (int s=0;s<14;s++){
                int ih = s/7, tap = s%7;
                short8 bfr = *reinterpret_cast<const short8*>(
                                &xs[(sub*16 + m + tap)*72 + ih*32 + kq*8]);
                acc[sub] = __builtin_amdgcn_mfma_f32_16x16x32_bf16(afr[s], bfr, acc[sub], 0,0,0);
            }
        }
        int ob = ot*16 + kq*4;
        float bv[4];
        #pragma unroll
        for (int r=0;r<4;r++) bv[r] = bias[ob + r];
        #pragma unroll
        for (int sub=0; sub<7; sub++){
            #pragma unroll
            for (int r=0;r<4;r++){
                float v = lk(acc[sub][r] + bv[r]);
                v = fmaxf(v, __shfl_xor(v, 1));
                v = fmaxf(v, __shfl_xor(v, 2));
                int pp = (sub*16 + n) >> 2;
                if (wrm && pp < 25)
                    p2[(size_t)(b*128 + ob + r)*125 + tile*25 + pp] = v;
            }
        }
    }
}

// ---------------------------------------------------------------------------
// Sliding column sums (unchanged)
// ---------------------------------------------------------------------------
__global__ __launch_bounds__(256) void k_colsum(const float* __restrict__ p2,
        float* __restrict__ ssum)
{
    int g = blockIdx.x*256 + threadIdx.x;
    int ic = g & 127, b = g >> 7;
    const float* pp = p2 + ((size_t)(b*128+ic))*125;
    float c = 0.f;
    for (int t=0;t<119;t++) c += pp[t];
    float* op = ssum + (size_t)(b*128+ic)*7;
    op[0] = c;
    #pragma unroll
    for (int s=0;s<6;s++){ c = c - pp[s] + pp[s+119]; op[s+1] = c; }
}

__global__ __launch_bounds__(128) void k_feat(const float* __restrict__ ssum,
        const float* __restrict__ w, const float* __restrict__ bias,
        float* __restrict__ feat)
{
    __shared__ float ss[896];
    int b = blockIdx.x, o = threadIdx.x;
    for (int j=threadIdx.x; j<896; j+=128) ss[j] = ssum[(size_t)b*896 + j];
    __syncthreads();
    const float* wp = w + o*896;
    float s = 0.f;
    for (int j=0;j<896;j++) s += wp[j]*ss[j];
    feat[b*128+o] = s*(1.f/119.f) + bias[o];
}

__global__ __launch_bounds__(64) void k_cls(const float* __restrict__ feat,
        const float* __restrict__ cw, const float* __restrict__ cb,
        float* __restrict__ out)
{
    __shared__ float lg[5];
    int b = blockIdx.x;
    if (threadIdx.x < 5){
        const float* fp = feat + b*128;
        const float* wp = cw + threadIdx.x*128;
        float s = 0.f;
        for (int o=0;o<128;o++) s += fp[o]*wp[o];
        lg[threadIdx.x] = s + cb[threadIdx.x];
    }
    __syncthreads();
    if (threadIdx.x == 0){
        float mx = -3.4e38f;
        for (int c=0;c<5;c++) mx = fmaxf(mx, lg[c]);
        float se = 0.f;
        for (int c=0;c<5;c++) se += expf(lg[c]-mx);
        float lse = mx + logf(se);
        for (int c=0;c<5;c++) out[b*5+c] = lg[c]-lse;
    }
}

extern "C" void kernel_launch(void* const* d_in, const int* in_sizes, int n_in,
                              void* d_out, int out_size, void* d_ws, size_t ws_size,
                              hipStream_t stream)
{
    const float* x   = (const float*)d_in[0];
    const float* hw1 = (const float*)d_in[2];
    const float* hb1 = (const float*)d_in[3];
    const float* hw2 = (const float*)d_in[4];
    const float* hb2 = (const float*)d_in[5];
    const float* hw3 = (const float*)d_in[6];
    const float* hb3 = (const float*)d_in[7];
    const float* hl1 = (const float*)d_in[8];
    const float* hl2 = (const float*)d_in[9];
    const float* gw  = (const float*)d_in[10];
    const float* gb0 = (const float*)d_in[11];
    const float* ew2 = (const float*)d_in[12];
    const float* eb2 = (const float*)d_in[13];
    const float* ew3 = (const float*)d_in[14];
    const float* eb3 = (const float*)d_in[15];
    const float* cw  = (const float*)d_in[16];
    const float* cb  = (const float*)d_in[17];
    float* out = (float*)d_out;

    float* f       = (float*)d_ws;
    float* latent  = f;
    float* h2      = f + 3932160;
    u16*   h1b     = (u16*)(f + 10223616);
    float* t1      = f + 786432;
    int*   idxb    = (int*)(f + 806432);
    float* n0f     = f + 808432;
    u16*   zpb     = (u16*)(f + 810000);
    float* p2      = f + 5000000;
    float* ssum    = f + 7100000;
    float* feat    = f + 7300000;

    k_hconv1<<<3072, 256, 0, stream>>>(x, hw1, hb1, h1b);
    k_hconv2<<<1024, 256, 0, stream>>>(h1b, hw2, hb2, h2);
    k_hconv3<<<512, 256, 0, stream>>>(h2, hw3, hb3, latent);
    k_lin1<<<768, 256, 0, stream>>>(latent, hl1, t1);
    k_topk<<<128, 128, 0, stream>>>(t1, hl2, idxb, n0f);
    k_gconv<<<512, 256, 0, stream>>>(x, idxb, n0f, gw, gb0, zpb);
    k_econv2<<<640, 256, 0, stream>>>(zpb, ew2, eb2, p2);
    k_colsum<<<64, 256, 0, stream>>>(p2, ssum);
    k_feat<<<128, 128, 0, stream>>>(ssum, ew3, eb3, feat);
    k_cls<<<128, 64, 0, stream>>>(feat, cw, cb, out);
}

// Round 8
// 471.950 us; speedup vs baseline: 4.0245x; 1.0422x over previous
//
#include <hip/hip_runtime.h>
#include <hip/hip_bf16.h>
#include <math.h>

typedef unsigned short u16;
typedef __attribute__((ext_vector_type(8))) short short8;
typedef __attribute__((ext_vector_type(4))) float floatx4;

__device__ __forceinline__ float lk(float v){ return v >= 0.f ? v : 0.01f*v; }
__device__ __forceinline__ u16 f2b(float f){
    __hip_bfloat16 h = __float2bfloat16(f);
    return *reinterpret_cast<u16*>(&h);
}

// ---------------------------------------------------------------------------
// Hypernet conv1 (MFMA bf16, positions-on-M): x[128,16,12288] f32 ->
// h1 bf16 [128,32,3072].  A = x windows (m = position), B = weights (n = o).
// C: row = kq*4+r = 4 consecutive positions -> in-register meanpool, no shfl.
// Block = (b, tile of 512 pos); 4 waves = (ohalf x thalf).
// ---------------------------------------------------------------------------
__global__ __launch_bounds__(256) void k_hconv1(const float* __restrict__ x,
        const float* __restrict__ w, const float* __restrict__ bias,
        u16* __restrict__ h1)
{
    __shared__ __align__(16) u16 xs[520*24];
    int b = blockIdx.x / 24, tile = blockIdx.x % 24;
    int g0 = tile*512;
    int tid = threadIdx.x;
    const float* xb = x + (size_t)b*16*12288;
    for (int row = tid; row < 520; row += 256){
        int t = g0 + row - 3;
        t = t < 0 ? -t : (t >= 12288 ? 2*12288-2-t : t);
        u16 v[16];
        #pragma unroll
        for (int ic=0;ic<16;ic++) v[ic] = f2b(xb[(size_t)ic*12288 + t]);
        short8 p0, p1;
        #pragma unroll
        for (int j=0;j<8;j++){ p0[j] = (short)v[j]; p1[j] = (short)v[8+j]; }
        *reinterpret_cast<short8*>(&xs[row*24])     = p0;
        *reinterpret_cast<short8*>(&xs[row*24 + 8]) = p1;
    }
    __syncthreads();
    int wv = tid >> 6, lane = tid & 63;
    int m = lane & 15, kq = lane >> 4;
    int ohalf = wv & 1, thalf = wv >> 1;
    int o = ohalf*16 + m;                      // B-frag n-dim = output channel
    short8 wfr[4];
    #pragma unroll
    for (int s=0;s<4;s++){
        int tap = 2*s + (kq>>1);
        #pragma unroll
        for (int j=0;j<8;j++){
            int ic = (kq&1)*8 + j;
            wfr[s][j] = (tap < 7) ? (short)f2b(w[(o*16+ic)*7 + tap]) : (short)0;
        }
    }
    floatx4 acc[16];
    #pragma unroll
    for (int i=0;i<16;i++) acc[i] = (floatx4){0.f,0.f,0.f,0.f};
    int tb0 = thalf*256;
    #pragma unroll
    for (int sub=0; sub<16; sub++){
        int tb = tb0 + sub*16;
        #pragma unroll
        for (int s=0;s<4;s++){
            int tap = 2*s + (kq>>1);
            short8 xfr = *reinterpret_cast<const short8*>(
                            &xs[(tb + m + tap)*24 + (kq&1)*8]);
            acc[sub] = __builtin_amdgcn_mfma_f32_16x16x32_bf16(xfr, wfr[s], acc[sub], 0,0,0);
        }
    }
    float bv = bias[o];
    size_t rowbase = (size_t)(b*32 + o)*3072 + tile*128 + thalf*64 + kq;
    #pragma unroll
    for (int sub=0; sub<16; sub++){
        float sum = lk(acc[sub][0]+bv) + lk(acc[sub][1]+bv)
                  + lk(acc[sub][2]+bv) + lk(acc[sub][3]+bv);
        h1[rowbase + sub*4] = f2b(sum*0.25f);
    }
}

// ---------------------------------------------------------------------------
// Hypernet conv2 (MFMA bf16, positions-on-M): h1 bf16 -> h2 f32 [128,64,768].
// Wave wv = o-tile of 16; 24 subtiles of 16 pos; 7 tap steps, k = 32 ic.
// ---------------------------------------------------------------------------
__global__ __launch_bounds__(256,1) void k_hconv2(const u16* __restrict__ h1,
        const float* __restrict__ w, const float* __restrict__ bias,
        float* __restrict__ h2)
{
    __shared__ __align__(16) u16 xs[390*40];
    int b = blockIdx.x >> 3, tile = blockIdx.x & 7;
    int g0 = tile*384;
    int tid = threadIdx.x;
    for (int row = tid; row < 390; row += 256){
        int t = g0 + row - 3;
        t = t < 0 ? -t : (t >= 3072 ? 2*3072-2-t : t);
        u16 v[32];
        #pragma unroll
        for (int ic=0;ic<32;ic++) v[ic] = h1[(size_t)(b*32+ic)*3072 + t];
        #pragma unroll
        for (int q=0;q<4;q++){
            short8 p;
            #pragma unroll
            for (int j=0;j<8;j++) p[j] = (short)v[q*8+j];
            *reinterpret_cast<short8*>(&xs[row*40 + q*8]) = p;
        }
    }
    __syncthreads();
    int wv = tid >> 6, lane = tid & 63;
    int m = lane & 15, kq = lane >> 4;
    int o = wv*16 + m;
    short8 wfr[7];
    #pragma unroll
    for (int s=0;s<7;s++){
        #pragma unroll
        for (int j=0;j<8;j++)
            wfr[s][j] = (short)f2b(w[(size_t)(o*32 + kq*8 + j)*7 + s]);
    }
    floatx4 acc[24];
    #pragma unroll
    for (int i=0;i<24;i++) acc[i] = (floatx4){0.f,0.f,0.f,0.f};
    for (int sub=0; sub<24; sub++){
        int tb = sub*16;
        #pragma unroll
        for (int s=0;s<7;s++){
            short8 xfr = *reinterpret_cast<const short8*>(
                            &xs[(tb + m + s)*40 + kq*8]);
            acc[sub] = __builtin_amdgcn_mfma_f32_16x16x32_bf16(xfr, wfr[s], acc[sub], 0,0,0);
        }
    }
    float bv = bias[o];
    size_t rowbase = (size_t)(b*64 + o)*768 + tile*96 + kq;
    #pragma unroll
    for (int sub=0; sub<24; sub++){
        float sum = lk(acc[sub][0]+bv) + lk(acc[sub][1]+bv)
                  + lk(acc[sub][2]+bv) + lk(acc[sub][3]+bv);
        h2[rowbase + sub*4] = sum*0.25f;
    }
}

// ---------------------------------------------------------------------------
// Hypernet conv3 FUSED: h2 f32 -> latent[128,6144]. (unchanged from round 7)
// ---------------------------------------------------------------------------
__global__ __launch_bounds__(256) void k_hconv3(const float* __restrict__ h2,
        const float* __restrict__ w, const float* __restrict__ bias,
        float* __restrict__ latent)
{
    __shared__ float xs[64*200];
    int b = blockIdx.x >> 2, tile = blockIdx.x & 3;
    int g0 = tile*192;
    int tid = threadIdx.x;
    const float* hb = h2 + (size_t)b*64*768;
    for (int idx = tid; idx < 64*198; idx += 256){
        int ic = idx / 198, jj = idx - ic*198;
        int t = g0 + jj - 3;
        t = t < 0 ? -t : (t >= 768 ? 2*768-2-t : t);
        xs[ic*200 + jj] = hb[(size_t)ic*768 + t];
    }
    __syncthreads();
    int c = tid >> 5, run = tid & 31;
    int p0 = run*6;
    float acc[6];
    #pragma unroll
    for (int l=0;l<6;l++) acc[l] = 0.f;
    for (int ic=0; ic<64; ic++){
        const float* wp = w + (c*64+ic)*7;
        float wr[7];
        #pragma unroll
        for (int s=0;s<7;s++) wr[s] = wp[s];
        const float* xr = xs + ic*200 + p0;
        float xw[12];
        #pragma unroll
        for (int j=0;j<12;j++) xw[j] = xr[j];
        #pragma unroll
        for (int s=0;s<7;s++)
            #pragma unroll
            for (int l=0;l<6;l++) acc[l] += wr[s]*xw[l+s];
    }
    float bv = bias[c];
    float* op = latent + (size_t)b*6144 + c*768 + g0 + p0;
    #pragma unroll
    for (int l=0;l<6;l++) op[l] = tanhf(acc[l] + bv);
}

// ---------------------------------------------------------------------------
// t1 = leaky(latent @ hl1^T).  (unchanged)
// ---------------------------------------------------------------------------
__global__ __launch_bounds__(256) void k_lin1(const float* __restrict__ latent,
        const float* __restrict__ hl1, float* __restrict__ t1)
{
    __shared__ float ls[6144];
    int b = blockIdx.x / 6, ntile = blockIdx.x % 6;
    int tid = threadIdx.x;
    const float4* lp = reinterpret_cast<const float4*>(latent + (size_t)b*6144);
    float4* lsv = reinterpret_cast<float4*>(ls);
    for (int i = tid; i < 1536; i += 256) lsv[i] = lp[i];
    __syncthreads();
    int wv = tid >> 6, lane = tid & 63;
    #pragma unroll
    for (int nn=0; nn<4; nn++){
        int n = ntile*16 + wv*4 + nn;
        const float4* wp = reinterpret_cast<const float4*>(hl1 + (size_t)n*6144);
        float s = 0.f;
        #pragma unroll
        for (int j=0;j<24;j++){
            float4 q = wp[lane + 64*j];
            float4 l4 = lsv[lane + 64*j];
            s += l4.x*q.x + l4.y*q.y + l4.z*q.z + l4.w*q.w;
        }
        #pragma unroll
        for (int off=32; off; off>>=1) s += __shfl_down(s, off);
        if (lane==0) t1[b*96+n] = lk(s);
    }
}

// ---------------------------------------------------------------------------
// logits = t1 @ hl2^T; top-5; n0 = #(idx<6)   (unchanged)
// ---------------------------------------------------------------------------
__global__ __launch_bounds__(128) void k_topk(const float* __restrict__ t1,
        const float* __restrict__ hl2, int* __restrict__ idxb, float* __restrict__ n0f)
{
    __shared__ float lg[96];
    int b = blockIdx.x, n = threadIdx.x;
    if (n < 96){
        float s = 0.f;
        const float* tp = t1 + b*96;
        const float* wp = hl2 + n*96;
        for (int m=0;m<96;m++) s += tp[m]*wp[m];
        lg[n] = s;
    }
    __syncthreads();
    if (threadIdx.x == 0){
        unsigned long long u0=0ull, u1=0ull;
        float n0 = 0.f;
        for (int k=0;k<5;k++){
            float best = -3.4e38f; int bi = 0;
            for (int m=0;m<96;m++){
                bool used = m<64 ? ((u0>>m)&1ull) : ((u1>>(m-64))&1ull);
                if (!used && lg[m] > best){ best = lg[m]; bi = m; }
            }
            if (bi<64) u0 |= 1ull<<bi; else u1 |= 1ull<<(bi-64);
            idxb[b*5+k] = bi;
            if (bi < 6) n0 += 1.f;
        }
        n0f[b] = n0;
    }
}

// ---------------------------------------------------------------------------
// Grouped idx conv ks=15 + bias + leaky + maxpool4 -> zp bf16 (unchanged)
// ---------------------------------------------------------------------------
__global__ __launch_bounds__(256) void k_gconv(const float* __restrict__ x,
        const int* __restrict__ idxb, const float* __restrict__ n0f,
        const float* __restrict__ gw, const float* __restrict__ gb0,
        u16* __restrict__ zp)
{
    __shared__ float xs[5][522];
    int b = blockIdx.x >> 2, qc = blockIdx.x & 3;
    int tid = threadIdx.x;
    int l0 = qc*508;
    for (int j=tid; j<5*522; j+=256){
        int k = j/522, u = j - k*522;
        int n = idxb[b*5+k];
        xs[k][u] = x[(size_t)b*196608 + n*2048 + l0 + u];
    }
    __syncthreads();
    int o = tid >> 2, qs = tid & 3;
    float wreg[5][15];
    #pragma unroll
    for (int k=0;k<5;k++){
        int n = idxb[b*5+k]; int gi = n/6;
        const float* wp = gw + gi*960 + o*15;
        #pragma unroll
        for (int s=0;s<15;s++) wreg[k][s] = wp[s];
    }
    float bv = n0f[b]*gb0[o];
    for (int q=qs; q<127; q+=4){
        int lb = 4*q;
        float s0=bv, s1=bv, s2=bv, s3=bv;
        #pragma unroll
        for (int k=0;k<5;k++){
            float xw[18];
            #pragma unroll
            for (int j=0;j<18;j++) xw[j] = xs[k][lb+j];
            #pragma unroll
            for (int sp=0;sp<15;sp++){
                s0 += wreg[k][sp]*xw[sp];
                s1 += wreg[k][sp]*xw[sp+1];
                s2 += wreg[k][sp]*xw[sp+2];
                s3 += wreg[k][sp]*xw[sp+3];
            }
        }
        float mx = fmaxf(fmaxf(lk(s0),lk(s1)), fmaxf(lk(s2),lk(s3)));
        zp[((size_t)(b*64+o))*508 + qc*127 + q] = f2b(mx);
    }
}

// ---------------------------------------------------------------------------
// Encoder conv2 (MFMA bf16, positions-on-M): zp bf16 -> p2 f32 [128,128,125].
// Pool = in-register max over C rows (4 consecutive conv positions).
// ---------------------------------------------------------------------------
__global__ __launch_bounds__(256,1) void k_econv2(const u16* __restrict__ zp,
        const float* __restrict__ w, const float* __restrict__ bias,
        float* __restrict__ p2)
{
    __shared__ __align__(16) u16 xs[118*72];
    int b = blockIdx.x / 5, tile = blockIdx.x % 5;
    int tid = threadIdx.x;
    if (tid < 118){
        int t = tile*100 + tid; if (t > 507) t = 507;
        u16 v[64];
        #pragma unroll
        for (int ic=0;ic<64;ic++) v[ic] = zp[(size_t)(b*64+ic)*508 + t];
        #pragma unroll
        for (int q=0;q<8;q++){
            short8 p;
            #pragma unroll
            for (int j=0;j<8;j++) p[j] = (short)v[q*8+j];
            *reinterpret_cast<short8*>(&xs[tid*72 + q*8]) = p;
        }
    }
    __syncthreads();
    int wv = tid >> 6, lane = tid & 63;
    int m = lane & 15, kq = lane >> 4;
    for (int half=0; half<2; half++){
        int ot = wv + 4*half;
        int o = ot*16 + m;
        short8 wfr[14];
        #pragma unroll
        for (int s=0;s<14;s++){
            int ih = s/7, tap = s%7;
            #pragma unroll
            for (int j=0;j<8;j++)
                wfr[s][j] = (short)f2b(w[(size_t)(o*64 + ih*32 + kq*8 + j)*7 + tap]);
        }
        floatx4 acc[7];
        #pragma unroll
        for (int i=0;i<7;i++) acc[i] = (floatx4){0.f,0.f,0.f,0.f};
        #pragma unroll
        for (int sub=0; sub<7; sub++){
            #pragma unroll
            for (int s=0;s<14;s++){
                int ih = s/7, tap = s%7;
                short8 xfr = *reinterpret_cast<const short8*>(
                                &xs[(sub*16 + m + tap)*72 + ih*32 + kq*8]);
                acc[sub] = __builtin_amdgcn_mfma_f32_16x16x32_bf16(xfr, wfr[s], acc[sub], 0,0,0);
            }
        }
        float bv = bias[o];
        #pragma unroll
        for (int sub=0; sub<7; sub++){
            int pidx = sub*4 + kq;
            if (pidx < 25){
                float mx = fmaxf(fmaxf(lk(acc[sub][0]+bv), lk(acc[sub][1]+bv)),
                                 fmaxf(lk(acc[sub][2]+bv), lk(acc[sub][3]+bv)));
                p2[(size_t)(b*128 + o)*125 + tile*25 + pidx] = mx;
            }
        }
    }
}

// ---------------------------------------------------------------------------
// Sliding column sums (unchanged)
// ---------------------------------------------------------------------------
__global__ __launch_bounds__(256) void k_colsum(const float* __restrict__ p2,
        float* __restrict__ ssum)
{
    int g = blockIdx.x*256 + threadIdx.x;
    int ic = g & 127, b = g >> 7;
    const float* pp = p2 + ((size_t)(b*128+ic))*125;
    float c = 0.f;
    for (int t=0;t<119;t++) c += pp[t];
    float* op = ssum + (size_t)(b*128+ic)*7;
    op[0] = c;
    #pragma unroll
    for (int s=0;s<6;s++){ c = c - pp[s] + pp[s+119]; op[s+1] = c; }
}

__global__ __launch_bounds__(128) void k_feat(const float* __restrict__ ssum,
        const float* __restrict__ w, const float* __restrict__ bias,
        float* __restrict__ feat)
{
    __shared__ float ss[896];
    int b = blockIdx.x, o = threadIdx.x;
    for (int j=threadIdx.x; j<896; j+=128) ss[j] = ssum[(size_t)b*896 + j];
    __syncthreads();
    const float* wp = w + o*896;
    float s = 0.f;
    for (int j=0;j<896;j++) s += wp[j]*ss[j];
    feat[b*128+o] = s*(1.f/119.f) + bias[o];
}

__global__ __launch_bounds__(64) void k_cls(const float* __restrict__ feat,
        const float* __restrict__ cw, const float* __restrict__ cb,
        float* __restrict__ out)
{
    __shared__ float lg[5];
    int b = blockIdx.x;
    if (threadIdx.x < 5){
        const float* fp = feat + b*128;
        const float* wp = cw + threadIdx.x*128;
        float s = 0.f;
        for (int o=0;o<128;o++) s += fp[o]*wp[o];
        lg[threadIdx.x] = s + cb[threadIdx.x];
    }
    __syncthreads();
    if (threadIdx.x == 0){
        float mx = -3.4e38f;
        for (int c=0;c<5;c++) mx = fmaxf(mx, lg[c]);
        float se = 0.f;
        for (int c=0;c<5;c++) se += expf(lg[c]-mx);
        float lse = mx + logf(se);
        for (int c=0;c<5;c++) out[b*5+c] = lg[c]-lse;
    }
}

extern "C" void kernel_launch(void* const* d_in, const int* in_sizes, int n_in,
                              void* d_out, int out_size, void* d_ws, size_t ws_size,
                              hipStream_t stream)
{
    const float* x   = (const float*)d_in[0];
    const float* hw1 = (const float*)d_in[2];
    const float* hb1 = (const float*)d_in[3];
    const float* hw2 = (const float*)d_in[4];
    const float* hb2 = (const float*)d_in[5];
    const float* hw3 = (const float*)d_in[6];
    const float* hb3 = (const float*)d_in[7];
    const float* hl1 = (const float*)d_in[8];
    const float* hl2 = (const float*)d_in[9];
    const float* gw  = (const float*)d_in[10];
    const float* gb0 = (const float*)d_in[11];
    const float* ew2 = (const float*)d_in[12];
    const float* eb2 = (const float*)d_in[13];
    const float* ew3 = (const float*)d_in[14];
    const float* eb3 = (const float*)d_in[15];
    const float* cw  = (const float*)d_in[16];
    const float* cb  = (const float*)d_in[17];
    float* out = (float*)d_out;

    float* f       = (float*)d_ws;
    float* latent  = f;
    float* h2      = f + 3932160;
    u16*   h1b     = (u16*)(f + 10223616);
    float* t1      = f + 786432;
    int*   idxb    = (int*)(f + 806432);
    float* n0f     = f + 808432;
    u16*   zpb     = (u16*)(f + 810000);
    float* p2      = f + 5000000;
    float* ssum    = f + 7100000;
    float* feat    = f + 7300000;

    k_hconv1<<<3072, 256, 0, stream>>>(x, hw1, hb1, h1b);
    k_hconv2<<<1024, 256, 0, stream>>>(h1b, hw2, hb2, h2);
    k_hconv3<<<512, 256, 0, stream>>>(h2, hw3, hb3, latent);
    k_lin1<<<768, 256, 0, stream>>>(latent, hl1, t1);
    k_topk<<<128, 128, 0, stream>>>(t1, hl2, idxb, n0f);
    k_gconv<<<512, 256, 0, stream>>>(x, idxb, n0f, gw, gb0, zpb);
    k_econv2<<<640, 256, 0, stream>>>(zpb, ew2, eb2, p2);
    k_colsum<<<64, 256, 0, stream>>>(p2, ssum);
    k_feat<<<128, 128, 0, stream>>>(ssum, ew3, eb3, feat);
    k_cls<<<128, 64, 0, stream>>>(feat, cw, cb, out);
}